// Round 1
// baseline (671.136 us; speedup 1.0000x reference)
//
#include <hip/hip_runtime.h>

// ---------------------------------------------------------------------------
// Model: 2-layer LSTM (BN=8192 seqs, T=64, F=16, H=128) + graph mixing stage.
// All GEMMs via v_mfma_f32_16x16x32_bf16.
// Fragment conventions (assumed, see round notes):
//   A-frag: lane l holds A[16*rt + (l&15)][32*kt + 8*(l>>4) + i], i=0..7
//   B-frag: lane l holds B[32*kt + 8*(l>>4) + i][16*ct + (l&15)]
//   D:      lane l, reg r holds D[16*rt + 4*(l>>4) + r][16*ct + (l&15)]
// ---------------------------------------------------------------------------

typedef __attribute__((ext_vector_type(4))) float f32x4;
typedef __attribute__((ext_vector_type(8))) __bf16 bf16x8;
typedef __attribute__((ext_vector_type(8))) unsigned short u16x8;
typedef __attribute__((ext_vector_type(4))) unsigned short u16x4;

#define DEV static __device__ __forceinline__

DEV unsigned short f2bf(float f) {
  unsigned u = __builtin_bit_cast(unsigned, f);
  u = u + 0x7fffu + ((u >> 16) & 1u);
  return (unsigned short)(u >> 16);
}
DEV float bf2f(unsigned short s) {
  unsigned u = ((unsigned)s) << 16;
  return __builtin_bit_cast(float, u);
}
DEV float sigm(float x) { return 1.f / (1.f + __expf(-x)); }
DEV float tanh_f(float x) { float e = __expf(2.f * x); return 1.f - 2.f / (e + 1.f); }

// ---------------- workspace layout (bytes) ----------------
#define O_W0PK   0            // 32ct*5kt*64l*8i bf16              = 163840 B
#define O_W1PK   163840       // 32ct*8kt*64l*8i bf16              = 262144 B
#define O_APK    425984       // 16ct*8kt*64l*8i bf16 (sigmoid(A)) = 131072 B
#define O_W1APK  557056       // 8rt*4kt*64l*8i bf16               =  32768 B
#define O_W2APK  589824
#define O_W3APK  622592
#define O_BIAS0  655360       // 512 f32
#define O_BIAS1  657408       // 512 f32
#define O_HTT    659456       // hT transposed [32][128][256] bf16 = 2 MiB
#define O_HAT    2756608      // HAt  [32][256][128] bf16
#define O_MIDT   4853760      // midT [32][256][128] bf16
#define O_W1HAT  6950912      // W1hA [32][256][128] bf16 (stored [b][n][g])
#define O_W3R    9048064      // W3r  [32][128][256] bf16 (row-major)
#define O_H1     11145216     // h1 chunk [4096][64][128] bf16     = 64 MiB
#define WS_NEED  (O_H1 + 67108864)

#define PREP_TOT 328704

// ---------------- prepass: pack weights into fragment-major bf16 ------------
__global__ void prep_kernel(const float* __restrict__ A,
    const float* __restrict__ Wih0, const float* __restrict__ Whh0,
    const float* __restrict__ bih0, const float* __restrict__ bhh0,
    const float* __restrict__ Wih1, const float* __restrict__ Whh1,
    const float* __restrict__ bih1, const float* __restrict__ bhh1,
    const float* __restrict__ W1, const float* __restrict__ W2,
    const float* __restrict__ W3, char* __restrict__ ws)
{
  int idx = blockIdx.x * blockDim.x + threadIdx.x;
  if (idx >= PREP_TOT) return;
  if (idx < 81920) {                       // W0pk: B[k][col], k: h(128)|x(16 pad 32)
    int o = idx, i = o & 7, l = (o >> 3) & 63, f = o >> 9;
    int kt = f % 5, ct = f / 5;
    int col = ct * 16 + (l & 15);
    float v;
    if (kt < 4) v = Whh0[col * 128 + 32 * kt + 8 * (l >> 4) + i];
    else { int kk = 8 * (l >> 4) + i; v = (kk < 16) ? Wih0[col * 16 + kk] : 0.f; }
    ((unsigned short*)(ws + O_W0PK))[idx] = f2bf(v);
  } else if (idx < 212992) {               // W1pk: k: h1(128)->Wih1 | h(128)->Whh1
    int o = idx - 81920, i = o & 7, l = (o >> 3) & 63, f = o >> 9;
    int kt = f & 7, ct = f >> 3;
    int col = ct * 16 + (l & 15);
    float v = (kt < 4) ? Wih1[col * 128 + 32 * kt + 8 * (l >> 4) + i]
                       : Whh1[col * 128 + 32 * (kt - 4) + 8 * (l >> 4) + i];
    ((unsigned short*)(ws + O_W1PK))[o] = f2bf(v);
  } else if (idx < 278528) {               // Apk: B[k=n][col=l] = sigmoid(A[n][l])
    int o = idx - 212992, i = o & 7, l = (o >> 3) & 63, f = o >> 9;
    int kt = f & 7, ct = f >> 3;
    int n = 32 * kt + 8 * (l >> 4) + i;
    int lc = 16 * ct + (l & 15);
    ((unsigned short*)(ws + O_APK))[o] = f2bf(sigm(A[n * 256 + lc]));
  } else if (idx < 327680) {               // W1/W2/W3 A-packs: A[g][k=h]
    int o = idx - 278528;
    int m = o >> 14;                       // 0..2 (16384 each)
    int oo = o & 16383;
    int i = oo & 7, l = (oo >> 3) & 63, f = oo >> 9;
    int kt = f & 3, rt = f >> 2;
    int g = 16 * rt + (l & 15);
    int k = 32 * kt + 8 * (l >> 4) + i;
    const float* W = (m == 0) ? W1 : (m == 1) ? W2 : W3;
    unsigned short* dst = (unsigned short*)(ws + ((m == 0) ? O_W1APK : (m == 1) ? O_W2APK : O_W3APK));
    dst[oo] = f2bf(W[g * 128 + k]);
  } else if (idx < 328192) {               // bias0
    int c = idx - 327680;
    ((float*)(ws + O_BIAS0))[c] = bih0[c] + bhh0[c];
  } else {                                 // bias1
    int c = idx - 328192;
    ((float*)(ws + O_BIAS1))[c] = bih1[c] + bhh1[c];
  }
}

// ---------------- LSTM layer 0 (persistent over T, 16 rows/block) -----------
// block: 512 thr = 8 waves; wave w owns units [16w,16w+16), gate coltiles p*8+w.
__global__ __launch_bounds__(512, 2) void lstm0_kernel(
    const float* __restrict__ x, char* __restrict__ ws, int row_base)
{
  const unsigned short* W0pk = (const unsigned short*)(ws + O_W0PK);
  const float* bias0 = (const float*)(ws + O_BIAS0);
  unsigned short* h1 = (unsigned short*)(ws + O_H1);

  int tid = threadIdx.x;
  int w = tid >> 6, l = tid & 63, lr = l & 15, lq = l >> 4;
  int brow = blockIdx.x * 16;              // chunk-local row base
  long grow0 = (long)row_base + brow;      // global row base

  __shared__ unsigned char hlds[4096];     // h state, XOR-swizzled
  ((unsigned long long*)hlds)[tid] = 0ull;

  bf16x8 Bf[4][5];
#pragma unroll
  for (int p = 0; p < 4; p++)
#pragma unroll
    for (int kt = 0; kt < 5; kt++)
      Bf[p][kt] = ((const bf16x8*)W0pk)[((p * 8 + w) * 5 + kt) * 64 + l];

  float bias_c[4];
#pragma unroll
  for (int p = 0; p < 4; p++) bias_c[p] = bias0[p * 128 + w * 16 + lr];
  float c_st[4] = {0.f, 0.f, 0.f, 0.f};
  __syncthreads();

  for (int t = 0; t < 64; t++) {
    bf16x8 haf[4];
#pragma unroll
    for (int kt = 0; kt < 4; kt++)
      haf[kt] = *(const bf16x8*)(hlds + lr * 256 + ((64 * kt + 16 * lq) ^ ((lr & 7) << 4)));
    u16x8 xu = (u16x8)0;
    if (lq < 2) {
      const float* xp = x + ((grow0 + lr) * 64 + t) * 16 + 8 * lq;
      float4 a = *(const float4*)xp;
      float4 b = *(const float4*)(xp + 4);
      xu[0] = f2bf(a.x); xu[1] = f2bf(a.y); xu[2] = f2bf(a.z); xu[3] = f2bf(a.w);
      xu[4] = f2bf(b.x); xu[5] = f2bf(b.y); xu[6] = f2bf(b.z); xu[7] = f2bf(b.w);
    }
    bf16x8 xaf = __builtin_bit_cast(bf16x8, xu);

    f32x4 acc[4];
#pragma unroll
    for (int p = 0; p < 4; p++) acc[p] = (f32x4){bias_c[p], bias_c[p], bias_c[p], bias_c[p]};
#pragma unroll
    for (int kt = 0; kt < 4; kt++)
#pragma unroll
      for (int p = 0; p < 4; p++)
        acc[p] = __builtin_amdgcn_mfma_f32_16x16x32_bf16(haf[kt], Bf[p][kt], acc[p], 0, 0, 0);
#pragma unroll
    for (int p = 0; p < 4; p++)
      acc[p] = __builtin_amdgcn_mfma_f32_16x16x32_bf16(xaf, Bf[p][4], acc[p], 0, 0, 0);

    // in-register cell update: gate order i,f,g,o
    unsigned short hb[4];
#pragma unroll
    for (int r = 0; r < 4; r++) {
      float c = sigm(acc[1][r]) * c_st[r] + sigm(acc[0][r]) * tanh_f(acc[2][r]);
      c_st[r] = c;
      hb[r] = f2bf(sigm(acc[3][r]) * tanh_f(c));
    }
    __syncthreads();                       // all waves done reading h_{t-1}
    int u = w * 16 + lr;
#pragma unroll
    for (int r = 0; r < 4; r++) {
      int row = 4 * lq + r;
      *(unsigned short*)(hlds + row * 256 + ((2 * u) ^ ((row & 7) << 4))) = hb[r];
      h1[(((long)(brow + row)) * 64 + t) * 128 + u] = hb[r];
    }
    __syncthreads();                       // h_t visible for next step
  }
}

// ---------------- LSTM layer 1 -------------------------------------------
__global__ __launch_bounds__(512, 2) void lstm1_kernel(char* __restrict__ ws, int row_base)
{
  const unsigned short* W1pk = (const unsigned short*)(ws + O_W1PK);
  const float* bias1 = (const float*)(ws + O_BIAS1);
  const unsigned short* h1 = (const unsigned short*)(ws + O_H1);
  unsigned short* hTt = (unsigned short*)(ws + O_HTT);

  int tid = threadIdx.x;
  int w = tid >> 6, l = tid & 63, lr = l & 15, lq = l >> 4;
  int brow = blockIdx.x * 16;
  long grow0 = (long)row_base + brow;

  __shared__ unsigned char hlds[4096];
  ((unsigned long long*)hlds)[tid] = 0ull;

  bf16x8 Bf[4][8];
#pragma unroll
  for (int p = 0; p < 4; p++)
#pragma unroll
    for (int kt = 0; kt < 8; kt++)
      Bf[p][kt] = ((const bf16x8*)W1pk)[((p * 8 + w) * 8 + kt) * 64 + l];

  float bias_c[4];
#pragma unroll
  for (int p = 0; p < 4; p++) bias_c[p] = bias1[p * 128 + w * 16 + lr];
  float c_st[4] = {0.f, 0.f, 0.f, 0.f};
  __syncthreads();

  for (int t = 0; t < 64; t++) {
    bf16x8 h1af[4];
#pragma unroll
    for (int kt = 0; kt < 4; kt++)
      h1af[kt] = *(const bf16x8*)(h1 + (((long)(brow + lr)) * 64 + t) * 128 + 32 * kt + 8 * lq);
    bf16x8 haf[4];
#pragma unroll
    for (int kt = 0; kt < 4; kt++)
      haf[kt] = *(const bf16x8*)(hlds + lr * 256 + ((64 * kt + 16 * lq) ^ ((lr & 7) << 4)));

    f32x4 acc[4];
#pragma unroll
    for (int p = 0; p < 4; p++) acc[p] = (f32x4){bias_c[p], bias_c[p], bias_c[p], bias_c[p]};
#pragma unroll
    for (int kt = 0; kt < 4; kt++)
#pragma unroll
      for (int p = 0; p < 4; p++)
        acc[p] = __builtin_amdgcn_mfma_f32_16x16x32_bf16(h1af[kt], Bf[p][kt], acc[p], 0, 0, 0);
#pragma unroll
    for (int kt = 0; kt < 4; kt++)
#pragma unroll
      for (int p = 0; p < 4; p++)
        acc[p] = __builtin_amdgcn_mfma_f32_16x16x32_bf16(haf[kt], Bf[p][4 + kt], acc[p], 0, 0, 0);

    unsigned short hb[4];
#pragma unroll
    for (int r = 0; r < 4; r++) {
      float c = sigm(acc[1][r]) * c_st[r] + sigm(acc[0][r]) * tanh_f(acc[2][r]);
      c_st[r] = c;
      hb[r] = f2bf(sigm(acc[3][r]) * tanh_f(c));
    }
    __syncthreads();
    int u = w * 16 + lr;
#pragma unroll
    for (int r = 0; r < 4; r++) {
      int row = 4 * lq + r;
      *(unsigned short*)(hlds + row * 256 + ((2 * u) ^ ((row & 7) << 4))) = hb[r];
      if (t == 63) {
        long grow = grow0 + row;
        long b = grow >> 8, n = grow & 255;
        hTt[(b * 128 + u) * 256 + n] = hb[r];  // h_LSTM[b][h][n]
      }
    }
    __syncthreads();
  }
}

// ---------------- graph stage --------------------------------------------
// G1: HA[b] = hTt[b] (128h x 256n) @ A_p (256n x 256l) -> HAt[b][l][h]
__global__ __launch_bounds__(256, 2) void g1_kernel(char* __restrict__ ws)
{
  const unsigned short* hTt = (const unsigned short*)(ws + O_HTT);
  const unsigned short* Apk = (const unsigned short*)(ws + O_APK);
  unsigned short* HAt = (unsigned short*)(ws + O_HAT);
  int tid = threadIdx.x, w = tid >> 6, l = tid & 63, lr = l & 15, lq = l >> 4;
  int b = blockIdx.x >> 2, rtp = blockIdx.x & 3;
  f32x4 acc[2][4];
#pragma unroll
  for (int i = 0; i < 2; i++)
#pragma unroll
    for (int j = 0; j < 4; j++) acc[i][j] = (f32x4){0.f, 0.f, 0.f, 0.f};
  for (int kt = 0; kt < 8; kt++) {
    bf16x8 af[2];
#pragma unroll
    for (int rtl = 0; rtl < 2; rtl++) {
      int rt = rtp * 2 + rtl;
      af[rtl] = *(const bf16x8*)(hTt + (long)(b * 128 + 16 * rt + lr) * 256 + 32 * kt + 8 * lq);
    }
#pragma unroll
    for (int cti = 0; cti < 4; cti++) {
      int ct = w * 4 + cti;
      bf16x8 bf = ((const bf16x8*)Apk)[(ct * 8 + kt) * 64 + l];
#pragma unroll
      for (int rtl = 0; rtl < 2; rtl++)
        acc[rtl][cti] = __builtin_amdgcn_mfma_f32_16x16x32_bf16(af[rtl], bf, acc[rtl][cti], 0, 0, 0);
    }
  }
#pragma unroll
  for (int rtl = 0; rtl < 2; rtl++)
#pragma unroll
    for (int cti = 0; cti < 4; cti++) {
      int rt = rtp * 2 + rtl, ct = w * 4 + cti;
      u16x4 pk;
#pragma unroll
      for (int r = 0; r < 4; r++) pk[r] = f2bf(acc[rtl][cti][r]);
      *(u16x4*)(HAt + (long)(b * 256 + 16 * ct + lr) * 128 + 16 * rt + 4 * lq) = pk;
    }
}

// G2: W1hA = W1 @ HA[b], mid = relu(W2 @ HA[b]); store both as [b][n][g]
__global__ __launch_bounds__(256, 2) void g2_kernel(char* __restrict__ ws)
{
  const unsigned short* HAt = (const unsigned short*)(ws + O_HAT);
  const unsigned short* W1apk = (const unsigned short*)(ws + O_W1APK);
  const unsigned short* W2apk = (const unsigned short*)(ws + O_W2APK);
  unsigned short* W1hAt = (unsigned short*)(ws + O_W1HAT);
  unsigned short* midT = (unsigned short*)(ws + O_MIDT);
  int tid = threadIdx.x, w = tid >> 6, l = tid & 63, lr = l & 15, lq = l >> 4;
  int b = blockIdx.x >> 2, rtp = blockIdx.x & 3;
  f32x4 a1[2][4], a2[2][4];
#pragma unroll
  for (int i = 0; i < 2; i++)
#pragma unroll
    for (int j = 0; j < 4; j++) { a1[i][j] = (f32x4){0.f,0.f,0.f,0.f}; a2[i][j] = (f32x4){0.f,0.f,0.f,0.f}; }
  for (int kt = 0; kt < 4; kt++) {
    bf16x8 af1[2], af2[2];
#pragma unroll
    for (int rtl = 0; rtl < 2; rtl++) {
      int rt = rtp * 2 + rtl;
      af1[rtl] = ((const bf16x8*)W1apk)[(rt * 4 + kt) * 64 + l];
      af2[rtl] = ((const bf16x8*)W2apk)[(rt * 4 + kt) * 64 + l];
    }
#pragma unroll
    for (int cti = 0; cti < 4; cti++) {
      int ct = w * 4 + cti;
      bf16x8 bf = *(const bf16x8*)(HAt + (long)(b * 256 + 16 * ct + lr) * 128 + 32 * kt + 8 * lq);
#pragma unroll
      for (int rtl = 0; rtl < 2; rtl++) {
        a1[rtl][cti] = __builtin_amdgcn_mfma_f32_16x16x32_bf16(af1[rtl], bf, a1[rtl][cti], 0, 0, 0);
        a2[rtl][cti] = __builtin_amdgcn_mfma_f32_16x16x32_bf16(af2[rtl], bf, a2[rtl][cti], 0, 0, 0);
      }
    }
  }
#pragma unroll
  for (int rtl = 0; rtl < 2; rtl++)
#pragma unroll
    for (int cti = 0; cti < 4; cti++) {
      int rt = rtp * 2 + rtl, ct = w * 4 + cti;
      u16x4 p1, p2;
#pragma unroll
      for (int r = 0; r < 4; r++) {
        p1[r] = f2bf(a1[rtl][cti][r]);
        p2[r] = f2bf(fmaxf(a2[rtl][cti][r], 0.f));
      }
      long off = (long)(b * 256 + 16 * ct + lr) * 128 + 16 * rt + 4 * lq;
      *(u16x4*)(W1hAt + off) = p1;
      *(u16x4*)(midT + off) = p2;
    }
}

// G3: W3r[b] = W3 @ mid[b]  -> row-major [b][f][n]
__global__ __launch_bounds__(256, 2) void g3_kernel(char* __restrict__ ws)
{
  const unsigned short* midT = (const unsigned short*)(ws + O_MIDT);
  const unsigned short* W3apk = (const unsigned short*)(ws + O_W3APK);
  unsigned short* W3r = (unsigned short*)(ws + O_W3R);
  int tid = threadIdx.x, w = tid >> 6, l = tid & 63, lr = l & 15, lq = l >> 4;
  int b = blockIdx.x >> 2, rtp = blockIdx.x & 3;
  f32x4 acc[2][4];
#pragma unroll
  for (int i = 0; i < 2; i++)
#pragma unroll
    for (int j = 0; j < 4; j++) acc[i][j] = (f32x4){0.f, 0.f, 0.f, 0.f};
  for (int kt = 0; kt < 4; kt++) {
    bf16x8 af[2];
#pragma unroll
    for (int rtl = 0; rtl < 2; rtl++)
      af[rtl] = ((const bf16x8*)W3apk)[((rtp * 2 + rtl) * 4 + kt) * 64 + l];
#pragma unroll
    for (int cti = 0; cti < 4; cti++) {
      int ct = w * 4 + cti;
      bf16x8 bf = *(const bf16x8*)(midT + (long)(b * 256 + 16 * ct + lr) * 128 + 32 * kt + 8 * lq);
#pragma unroll
      for (int rtl = 0; rtl < 2; rtl++)
        acc[rtl][cti] = __builtin_amdgcn_mfma_f32_16x16x32_bf16(af[rtl], bf, acc[rtl][cti], 0, 0, 0);
    }
  }
#pragma unroll
  for (int rtl = 0; rtl < 2; rtl++)
#pragma unroll
    for (int cti = 0; cti < 4; cti++) {
      int rt = rtp * 2 + rtl, ct = w * 4 + cti;
#pragma unroll
      for (int r = 0; r < 4; r++)
        W3r[(long)(b * 128 + 16 * rt + 4 * lq + r) * 256 + 16 * ct + lr] = f2bf(acc[rtl][cti][r]);
    }
}

// G4: ATW = W3r[b] @ A_p; h_out = 0.1*ATW + 0.9*W1hA; out = sigmoid(Wfc . h_out)
__global__ __launch_bounds__(256, 2) void g4_kernel(char* __restrict__ ws,
    const float* __restrict__ Wfc, float* __restrict__ out)
{
  const unsigned short* W3r = (const unsigned short*)(ws + O_W3R);
  const unsigned short* Apk = (const unsigned short*)(ws + O_APK);
  const unsigned short* W1hAt = (const unsigned short*)(ws + O_W1HAT);
  int tid = threadIdx.x, w = tid >> 6, l = tid & 63, lr = l & 15, lq = l >> 4;
  int b = blockIdx.x;
  f32x4 acc[8][4];
#pragma unroll
  for (int i = 0; i < 8; i++)
#pragma unroll
    for (int j = 0; j < 4; j++) acc[i][j] = (f32x4){0.f, 0.f, 0.f, 0.f};
  for (int kt = 0; kt < 8; kt++) {
    bf16x8 af[8];
#pragma unroll
    for (int rt = 0; rt < 8; rt++)
      af[rt] = *(const bf16x8*)(W3r + (long)(b * 128 + 16 * rt + lr) * 256 + 32 * kt + 8 * lq);
#pragma unroll
    for (int cti = 0; cti < 4; cti++) {
      int ct = w * 4 + cti;
      bf16x8 bf = ((const bf16x8*)Apk)[(ct * 8 + kt) * 64 + l];
#pragma unroll
      for (int rt = 0; rt < 8; rt++)
        acc[rt][cti] = __builtin_amdgcn_mfma_f32_16x16x32_bf16(af[rt], bf, acc[rt][cti], 0, 0, 0);
    }
  }
  float psum[4] = {0.f, 0.f, 0.f, 0.f};
#pragma unroll
  for (int rt = 0; rt < 8; rt++) {
    float4 wf = *(const float4*)(Wfc + 16 * rt + 4 * lq);
    float wfa[4] = {wf.x, wf.y, wf.z, wf.w};
#pragma unroll
    for (int cti = 0; cti < 4; cti++) {
      int ct = w * 4 + cti;
      u16x4 wv = *(const u16x4*)(W1hAt + (long)(b * 256 + 16 * ct + lr) * 128 + 16 * rt + 4 * lq);
#pragma unroll
      for (int r = 0; r < 4; r++) {
        float hout = 0.1f * acc[rt][cti][r] + 0.9f * bf2f(wv[r]);
        psum[cti] += wfa[r] * hout;
      }
    }
  }
#pragma unroll
  for (int cti = 0; cti < 4; cti++) {
    float s = psum[cti];
    s += __shfl_xor(s, 16);
    s += __shfl_xor(s, 32);
    if (lq == 0) out[b * 256 + 16 * (w * 4 + cti) + lr] = 1.f / (1.f + __expf(-s));
  }
}

// ---------------------------------------------------------------------------
extern "C" void kernel_launch(void* const* d_in, const int* in_sizes, int n_in,
                              void* d_out, int out_size, void* d_ws, size_t ws_size,
                              hipStream_t stream)
{
  const float* x    = (const float*)d_in[0];
  const float* A    = (const float*)d_in[1];
  const float* Wih0 = (const float*)d_in[2];
  const float* Whh0 = (const float*)d_in[3];
  const float* bih0 = (const float*)d_in[4];
  const float* bhh0 = (const float*)d_in[5];
  const float* Wih1 = (const float*)d_in[6];
  const float* Whh1 = (const float*)d_in[7];
  const float* bih1 = (const float*)d_in[8];
  const float* bhh1 = (const float*)d_in[9];
  const float* W1   = (const float*)d_in[10];
  const float* W2   = (const float*)d_in[11];
  const float* W3   = (const float*)d_in[12];
  const float* Wfc  = (const float*)d_in[13];
  char* ws = (char*)d_ws;

  prep_kernel<<<(PREP_TOT + 255) / 256, 256, 0, stream>>>(
      A, Wih0, Whh0, bih0, bhh0, Wih1, Whh1, bih1, bhh1, W1, W2, W3, ws);

  // two chunks of 4096 rows (64 MiB h1 staging buffer reused)
  for (int c = 0; c < 2; c++) {
    lstm0_kernel<<<256, 512, 0, stream>>>(x, ws, c * 4096);
    lstm1_kernel<<<256, 512, 0, stream>>>(ws, c * 4096);
  }

  g1_kernel<<<128, 256, 0, stream>>>(ws);
  g2_kernel<<<128, 256, 0, stream>>>(ws);
  g3_kernel<<<128, 256, 0, stream>>>(ws);
  g4_kernel<<<32, 256, 0, stream>>>(ws, Wfc, (float*)d_out);
}

// Round 2
// 489.249 us; speedup vs baseline: 1.3718x; 1.3718x over previous
//
#include <hip/hip_runtime.h>

// ---------------------------------------------------------------------------
// 2-layer LSTM (BN=8192 seqs, T=64, F=16, H=128) + graph mixing stage.
// MFMA v_mfma_f32_16x16x32_bf16 everywhere.
//   A-frag: lane l holds A[16*rt + (l&15)][32*kt + 8*(l>>4) + i], i=0..7
//   B-frag: lane l holds B[32*kt + 8*(l>>4) + i][16*ct + (l&15)]
//   D:      lane l, reg r holds D[16*rt + 4*(l>>4) + r][16*ct + (l&15)]
// ---------------------------------------------------------------------------

typedef __attribute__((ext_vector_type(4))) float f32x4;
typedef __attribute__((ext_vector_type(8))) __bf16 bf16x8;
typedef __attribute__((ext_vector_type(8))) unsigned short u16x8;
typedef __attribute__((ext_vector_type(4))) unsigned short u16x4;

#define DEV static __device__ __forceinline__

DEV unsigned short f2bf(float f) {
  unsigned u = __builtin_bit_cast(unsigned, f);
  u = u + 0x7fffu + ((u >> 16) & 1u);
  return (unsigned short)(u >> 16);
}
DEV float bf2f(unsigned short s) {
  unsigned u = ((unsigned)s) << 16;
  return __builtin_bit_cast(float, u);
}

// Fast LSTM cell: v_exp_f32 + v_rcp_f32 only (no IEEE divides). |gates| << 40
// so exp2 never overflows into the NaN-producing regime.
DEV float cell(float gi, float gf, float gg, float go, float& c) {
  const float K1 = 1.44269504f, K2 = 2.88539008f;
  float ei = exp2f(-K1 * gi);
  float ef = exp2f(-K1 * gf);
  float eg = exp2f(K2 * gg);
  float eo = exp2f(-K1 * go);
  float tg = 1.f - 2.f * __builtin_amdgcn_rcpf(eg + 1.f);
  c = __builtin_amdgcn_rcpf(1.f + ef) * c + __builtin_amdgcn_rcpf(1.f + ei) * tg;
  float ec = exp2f(K2 * c);
  float tc = 1.f - 2.f * __builtin_amdgcn_rcpf(ec + 1.f);
  return __builtin_amdgcn_rcpf(1.f + eo) * tc;
}

// ---------------- workspace layout (bytes) ----------------
#define O_W0PK   0            // 163840
#define O_W1PK   163840       // 262144
#define O_APK    425984       // 131072
#define O_W1APK  557056       // 32768
#define O_W2APK  589824       // 32768
#define O_W3APK  622592       // 32768
#define O_BIAS0  655360       // 2048
#define O_BIAS1  657408       // 2048
#define O_HTT    659456       // 2097152  hT^T [32][128][256] bf16
#define O_HAT    2756608      // 2097152  HAt  [32][256][128] bf16
#define O_MIDT   4853760      // 2097152
#define O_W1HAT  6950912      // 2097152
#define O_W3R    9048064      // 2097152
#define O_XPK    11145216     // 33554432 x fragments (padded K=32)
#define O_H1     44699648     // up to 128 MiB h1 [row][t][128] bf16

#define PREP_TOT 328704

// ---------------- prepass: pack weights into fragment-major bf16 ------------
__global__ void prep_kernel(const float* __restrict__ A,
    const float* __restrict__ Wih0, const float* __restrict__ Whh0,
    const float* __restrict__ bih0, const float* __restrict__ bhh0,
    const float* __restrict__ Wih1, const float* __restrict__ Whh1,
    const float* __restrict__ bih1, const float* __restrict__ bhh1,
    const float* __restrict__ W1, const float* __restrict__ W2,
    const float* __restrict__ W3, char* __restrict__ ws)
{
  int idx = blockIdx.x * blockDim.x + threadIdx.x;
  if (idx >= PREP_TOT) return;
  if (idx < 81920) {                       // W0pk
    int o = idx, i = o & 7, l = (o >> 3) & 63, f = o >> 9;
    int kt = f % 5, ct = f / 5;
    int col = ct * 16 + (l & 15);
    float v;
    if (kt < 4) v = Whh0[col * 128 + 32 * kt + 8 * (l >> 4) + i];
    else { int kk = 8 * (l >> 4) + i; v = (kk < 16) ? Wih0[col * 16 + kk] : 0.f; }
    ((unsigned short*)(ws + O_W0PK))[idx] = f2bf(v);
  } else if (idx < 212992) {               // W1pk
    int o = idx - 81920, i = o & 7, l = (o >> 3) & 63, f = o >> 9;
    int kt = f & 7, ct = f >> 3;
    int col = ct * 16 + (l & 15);
    float v = (kt < 4) ? Wih1[col * 128 + 32 * kt + 8 * (l >> 4) + i]
                       : Whh1[col * 128 + 32 * (kt - 4) + 8 * (l >> 4) + i];
    ((unsigned short*)(ws + O_W1PK))[o] = f2bf(v);
  } else if (idx < 278528) {               // Apk = sigmoid(A) B-frags
    int o = idx - 212992, i = o & 7, l = (o >> 3) & 63, f = o >> 9;
    int kt = f & 7, ct = f >> 3;
    int n = 32 * kt + 8 * (l >> 4) + i;
    int lc = 16 * ct + (l & 15);
    float e = exp2f(-1.44269504f * A[n * 256 + lc]);
    ((unsigned short*)(ws + O_APK))[o] = f2bf(__builtin_amdgcn_rcpf(1.f + e));
  } else if (idx < 327680) {               // W1/W2/W3 A-frags
    int o = idx - 278528;
    int m = o >> 14;
    int oo = o & 16383;
    int i = oo & 7, l = (oo >> 3) & 63, f = oo >> 9;
    int kt = f & 3, rt = f >> 2;
    int g = 16 * rt + (l & 15);
    int k = 32 * kt + 8 * (l >> 4) + i;
    const float* W = (m == 0) ? W1 : (m == 1) ? W2 : W3;
    unsigned short* dst = (unsigned short*)(ws + ((m == 0) ? O_W1APK : (m == 1) ? O_W2APK : O_W3APK));
    dst[oo] = f2bf(W[g * 128 + k]);
  } else if (idx < 328192) {
    int c = idx - 327680;
    ((float*)(ws + O_BIAS0))[c] = bih0[c] + bhh0[c];
  } else {
    int c = idx - 328192;
    ((float*)(ws + O_BIAS1))[c] = bih1[c] + bhh1[c];
  }
}

// x -> padded A-fragment bf16: xpk[((row>>4)*64 + t)*64 + lane]*8
__global__ void prepx_kernel(const float* __restrict__ x, char* __restrict__ ws)
{
  int tid = blockIdx.x * 256 + threadIdx.x;     // 0 .. 2097151
  int dat = (tid < 1048576) ? 1 : 0;
  int id = tid & 1048575;
  int half = id & 1, t = (id >> 1) & 63, row = id >> 7;
  u16x8 v = (u16x8)0;
  if (dat) {
    const float* p = x + ((long)row * 64 + t) * 16 + 8 * half;
    float4 a = *(const float4*)p;
    float4 b = *(const float4*)(p + 4);
    v[0] = f2bf(a.x); v[1] = f2bf(a.y); v[2] = f2bf(a.z); v[3] = f2bf(a.w);
    v[4] = f2bf(b.x); v[5] = f2bf(b.y); v[6] = f2bf(b.z); v[7] = f2bf(b.w);
  }
  int lane = (dat ? 0 : 32) + half * 16 + (row & 15);
  int rt = row >> 4;
  ((u16x8*)(ws + O_XPK))[(rt * 64 + t) * 64 + lane] = v;
}

// ---------------- LSTM layer 0: 16*NRT rows/block, 1 barrier/step ----------
template<int NRT>
__global__ __launch_bounds__(512, 2) void lstm0_t(char* __restrict__ ws, int row_base)
{
  const unsigned short* W0pk = (const unsigned short*)(ws + O_W0PK);
  const float* bias0 = (const float*)(ws + O_BIAS0);
  const unsigned short* xpk = (const unsigned short*)(ws + O_XPK);
  unsigned short* h1 = (unsigned short*)(ws + O_H1);

  int tid = threadIdx.x;
  int w = tid >> 6, l = tid & 63, lr = l & 15, lq = l >> 4;
  int lrow = blockIdx.x * (16 * NRT);
  long grow0 = (long)row_base + lrow;

  __shared__ unsigned char hlds[2][NRT * 4096];
  if (tid * 16 < NRT * 4096) ((u16x8*)hlds[0])[tid] = (u16x8)0;

  bf16x8 Bf[4][5];
#pragma unroll
  for (int p = 0; p < 4; p++)
#pragma unroll
    for (int kt = 0; kt < 5; kt++)
      Bf[p][kt] = ((const bf16x8*)W0pk)[((p * 8 + w) * 5 + kt) * 64 + l];

  float bias_c[4];
#pragma unroll
  for (int p = 0; p < 4; p++) bias_c[p] = bias0[p * 128 + w * 16 + lr];
  float c_st[NRT][4];
#pragma unroll
  for (int rt = 0; rt < NRT; rt++)
#pragma unroll
    for (int r = 0; r < 4; r++) c_st[rt][r] = 0.f;

  int u = w * 16 + lr;
  int rd[NRT][4], wr[NRT][4];
  const bf16x8* xp[NRT];
  unsigned short* h1p[NRT];
#pragma unroll
  for (int rt = 0; rt < NRT; rt++) {
#pragma unroll
    for (int kt = 0; kt < 4; kt++)
      rd[rt][kt] = (16 * rt + lr) * 256 + ((64 * kt + 16 * lq) ^ ((lr & 7) << 4));
#pragma unroll
    for (int r = 0; r < 4; r++)
      wr[rt][r] = (16 * rt + 4 * lq + r) * 256 + ((2 * u) ^ (((4 * lq + r) & 7) << 4));
    xp[rt] = (const bf16x8*)xpk + ((grow0 >> 4) + rt) * 4096 + l;
    h1p[rt] = h1 + ((long)(lrow + 16 * rt + 4 * lq)) * 8192 + u;
  }
  __syncthreads();

  for (int t = 0; t < 64; t++) {
    const unsigned char* rbuf = hlds[t & 1];
    unsigned char* wbuf = hlds[(t & 1) ^ 1];
#pragma unroll
    for (int rt = 0; rt < NRT; rt++) {
      bf16x8 xa = xp[rt][t * 64];
      bf16x8 ha[4];
#pragma unroll
      for (int kt = 0; kt < 4; kt++) ha[kt] = *(const bf16x8*)(rbuf + rd[rt][kt]);
      f32x4 acc[4];
#pragma unroll
      for (int p = 0; p < 4; p++) acc[p] = (f32x4){bias_c[p], bias_c[p], bias_c[p], bias_c[p]};
#pragma unroll
      for (int kt = 0; kt < 4; kt++)
#pragma unroll
        for (int p = 0; p < 4; p++)
          acc[p] = __builtin_amdgcn_mfma_f32_16x16x32_bf16(ha[kt], Bf[p][kt], acc[p], 0, 0, 0);
#pragma unroll
      for (int p = 0; p < 4; p++)
        acc[p] = __builtin_amdgcn_mfma_f32_16x16x32_bf16(xa, Bf[p][4], acc[p], 0, 0, 0);
#pragma unroll
      for (int r = 0; r < 4; r++) {
        float h = cell(acc[0][r], acc[1][r], acc[2][r], acc[3][r], c_st[rt][r]);
        unsigned short hb = f2bf(h);
        *(unsigned short*)(wbuf + wr[rt][r]) = hb;
        h1p[rt][r * 8192 + t * 128] = hb;
      }
    }
    __syncthreads();
  }
}

// ---------------- LSTM layer 1 -------------------------------------------
template<int NRT>
__global__ __launch_bounds__(512, 2) void lstm1_t(char* __restrict__ ws, int row_base)
{
  const unsigned short* W1pk = (const unsigned short*)(ws + O_W1PK);
  const float* bias1 = (const float*)(ws + O_BIAS1);
  const unsigned short* h1 = (const unsigned short*)(ws + O_H1);
  unsigned short* hTt = (unsigned short*)(ws + O_HTT);

  int tid = threadIdx.x;
  int w = tid >> 6, l = tid & 63, lr = l & 15, lq = l >> 4;
  int lrow = blockIdx.x * (16 * NRT);
  long grow0 = (long)row_base + lrow;

  __shared__ unsigned char hlds[2][NRT * 4096];
  if (tid * 16 < NRT * 4096) ((u16x8*)hlds[0])[tid] = (u16x8)0;

  bf16x8 Bf[4][8];
#pragma unroll
  for (int p = 0; p < 4; p++)
#pragma unroll
    for (int kt = 0; kt < 8; kt++)
      Bf[p][kt] = ((const bf16x8*)W1pk)[((p * 8 + w) * 8 + kt) * 64 + l];

  float bias_c[4];
#pragma unroll
  for (int p = 0; p < 4; p++) bias_c[p] = bias1[p * 128 + w * 16 + lr];
  float c_st[NRT][4];
#pragma unroll
  for (int rt = 0; rt < NRT; rt++)
#pragma unroll
    for (int r = 0; r < 4; r++) c_st[rt][r] = 0.f;

  int u = w * 16 + lr;
  int rd[NRT][4], wr[NRT][4];
  const unsigned short* h1p[NRT];
#pragma unroll
  for (int rt = 0; rt < NRT; rt++) {
#pragma unroll
    for (int kt = 0; kt < 4; kt++)
      rd[rt][kt] = (16 * rt + lr) * 256 + ((64 * kt + 16 * lq) ^ ((lr & 7) << 4));
#pragma unroll
    for (int r = 0; r < 4; r++)
      wr[rt][r] = (16 * rt + 4 * lq + r) * 256 + ((2 * u) ^ (((4 * lq + r) & 7) << 4));
    h1p[rt] = h1 + ((long)(lrow + 16 * rt + lr)) * 8192 + 8 * lq;
  }
  __syncthreads();

  for (int t = 0; t < 64; t++) {
    const unsigned char* rbuf = hlds[t & 1];
    unsigned char* wbuf = hlds[(t & 1) ^ 1];
    // issue all global h1 loads up front (latency overlaps rt=0 MFMA work)
    bf16x8 h1a[NRT][4];
#pragma unroll
    for (int rt = 0; rt < NRT; rt++)
#pragma unroll
      for (int kt = 0; kt < 4; kt++)
        h1a[rt][kt] = *(const bf16x8*)(h1p[rt] + t * 128 + 32 * kt);
#pragma unroll
    for (int rt = 0; rt < NRT; rt++) {
      bf16x8 ha[4];
#pragma unroll
      for (int kt = 0; kt < 4; kt++) ha[kt] = *(const bf16x8*)(rbuf + rd[rt][kt]);
      f32x4 acc[4];
#pragma unroll
      for (int p = 0; p < 4; p++) acc[p] = (f32x4){bias_c[p], bias_c[p], bias_c[p], bias_c[p]};
#pragma unroll
      for (int kt = 0; kt < 4; kt++)
#pragma unroll
        for (int p = 0; p < 4; p++)
          acc[p] = __builtin_amdgcn_mfma_f32_16x16x32_bf16(h1a[rt][kt], Bf[p][kt], acc[p], 0, 0, 0);
#pragma unroll
      for (int kt = 0; kt < 4; kt++)
#pragma unroll
        for (int p = 0; p < 4; p++)
          acc[p] = __builtin_amdgcn_mfma_f32_16x16x32_bf16(ha[kt], Bf[p][4 + kt], acc[p], 0, 0, 0);
#pragma unroll
      for (int r = 0; r < 4; r++) {
        float h = cell(acc[0][r], acc[1][r], acc[2][r], acc[3][r], c_st[rt][r]);
        unsigned short hb = f2bf(h);
        *(unsigned short*)(wbuf + wr[rt][r]) = hb;
        if (t == 63) {
          long grow = grow0 + 16 * rt + 4 * lq + r;
          hTt[((grow >> 8) * 128 + u) * 256 + (grow & 255)] = hb;
        }
      }
    }
    __syncthreads();
  }
}

// ---------------- graph stage --------------------------------------------
// G1: HA[b] = hTt[b] @ A_p -> HAt[b][l][h]
__global__ __launch_bounds__(256, 2) void g1_kernel(char* __restrict__ ws)
{
  const unsigned short* hTt = (const unsigned short*)(ws + O_HTT);
  const unsigned short* Apk = (const unsigned short*)(ws + O_APK);
  unsigned short* HAt = (unsigned short*)(ws + O_HAT);
  int tid = threadIdx.x, w = tid >> 6, l = tid & 63, lr = l & 15, lq = l >> 4;
  int bi = blockIdx.x;
  int b = bi >> 3, rtp = (bi >> 1) & 3, ch = bi & 1;
  f32x4 acc[2][2];
#pragma unroll
  for (int i = 0; i < 2; i++)
#pragma unroll
    for (int j = 0; j < 2; j++) acc[i][j] = (f32x4){0.f, 0.f, 0.f, 0.f};
  for (int kt = 0; kt < 8; kt++) {
    bf16x8 af[2];
#pragma unroll
    for (int rtl = 0; rtl < 2; rtl++) {
      int rt = rtp * 2 + rtl;
      af[rtl] = *(const bf16x8*)(hTt + (long)(b * 128 + 16 * rt + lr) * 256 + 32 * kt + 8 * lq);
    }
#pragma unroll
    for (int cti = 0; cti < 2; cti++) {
      int ct = w * 4 + ch * 2 + cti;
      bf16x8 bf = ((const bf16x8*)Apk)[(ct * 8 + kt) * 64 + l];
#pragma unroll
      for (int rtl = 0; rtl < 2; rtl++)
        acc[rtl][cti] = __builtin_amdgcn_mfma_f32_16x16x32_bf16(af[rtl], bf, acc[rtl][cti], 0, 0, 0);
    }
  }
#pragma unroll
  for (int rtl = 0; rtl < 2; rtl++)
#pragma unroll
    for (int cti = 0; cti < 2; cti++) {
      int rt = rtp * 2 + rtl, ct = w * 4 + ch * 2 + cti;
      u16x4 pk;
#pragma unroll
      for (int r = 0; r < 4; r++) pk[r] = f2bf(acc[rtl][cti][r]);
      *(u16x4*)(HAt + (long)(b * 256 + 16 * ct + lr) * 128 + 16 * rt + 4 * lq) = pk;
    }
}

// G2: W1hA = W1 @ HA[b], mid = relu(W2 @ HA[b]); store as [b][n][g]
__global__ __launch_bounds__(256, 2) void g2_kernel(char* __restrict__ ws)
{
  const unsigned short* HAt = (const unsigned short*)(ws + O_HAT);
  const unsigned short* W1apk = (const unsigned short*)(ws + O_W1APK);
  const unsigned short* W2apk = (const unsigned short*)(ws + O_W2APK);
  unsigned short* W1hAt = (unsigned short*)(ws + O_W1HAT);
  unsigned short* midT = (unsigned short*)(ws + O_MIDT);
  int tid = threadIdx.x, w = tid >> 6, l = tid & 63, lr = l & 15, lq = l >> 4;
  int bi = blockIdx.x;
  int b = bi >> 3, rtp = (bi >> 1) & 3, ch = bi & 1;
  f32x4 a1[2][2], a2[2][2];
#pragma unroll
  for (int i = 0; i < 2; i++)
#pragma unroll
    for (int j = 0; j < 2; j++) { a1[i][j] = (f32x4){0.f,0.f,0.f,0.f}; a2[i][j] = (f32x4){0.f,0.f,0.f,0.f}; }
  for (int kt = 0; kt < 4; kt++) {
    bf16x8 af1[2], af2[2];
#pragma unroll
    for (int rtl = 0; rtl < 2; rtl++) {
      int rt = rtp * 2 + rtl;
      af1[rtl] = ((const bf16x8*)W1apk)[(rt * 4 + kt) * 64 + l];
      af2[rtl] = ((const bf16x8*)W2apk)[(rt * 4 + kt) * 64 + l];
    }
#pragma unroll
    for (int cti = 0; cti < 2; cti++) {
      int ct = w * 4 + ch * 2 + cti;
      bf16x8 bf = *(const bf16x8*)(HAt + (long)(b * 256 + 16 * ct + lr) * 128 + 32 * kt + 8 * lq);
#pragma unroll
      for (int rtl = 0; rtl < 2; rtl++) {
        a1[rtl][cti] = __builtin_amdgcn_mfma_f32_16x16x32_bf16(af1[rtl], bf, a1[rtl][cti], 0, 0, 0);
        a2[rtl][cti] = __builtin_amdgcn_mfma_f32_16x16x32_bf16(af2[rtl], bf, a2[rtl][cti], 0, 0, 0);
      }
    }
  }
#pragma unroll
  for (int rtl = 0; rtl < 2; rtl++)
#pragma unroll
    for (int cti = 0; cti < 2; cti++) {
      int rt = rtp * 2 + rtl, ct = w * 4 + ch * 2 + cti;
      u16x4 p1, p2;
#pragma unroll
      for (int r = 0; r < 4; r++) {
        p1[r] = f2bf(a1[rtl][cti][r]);
        p2[r] = f2bf(fmaxf(a2[rtl][cti][r], 0.f));
      }
      long off = (long)(b * 256 + 16 * ct + lr) * 128 + 16 * rt + 4 * lq;
      *(u16x4*)(W1hAt + off) = p1;
      *(u16x4*)(midT + off) = p2;
    }
}

// G3: W3r[b] = W3 @ mid[b] -> row-major [b][f][n]
__global__ __launch_bounds__(256, 2) void g3_kernel(char* __restrict__ ws)
{
  const unsigned short* midT = (const unsigned short*)(ws + O_MIDT);
  const unsigned short* W3apk = (const unsigned short*)(ws + O_W3APK);
  unsigned short* W3r = (unsigned short*)(ws + O_W3R);
  int tid = threadIdx.x, w = tid >> 6, l = tid & 63, lr = l & 15, lq = l >> 4;
  int bi = blockIdx.x;
  int b = bi >> 3, rtp = (bi >> 1) & 3, ch = bi & 1;
  f32x4 acc[2][2];
#pragma unroll
  for (int i = 0; i < 2; i++)
#pragma unroll
    for (int j = 0; j < 2; j++) acc[i][j] = (f32x4){0.f, 0.f, 0.f, 0.f};
  for (int kt = 0; kt < 4; kt++) {
    bf16x8 af[2];
#pragma unroll
    for (int rtl = 0; rtl < 2; rtl++)
      af[rtl] = ((const bf16x8*)W3apk)[((rtp * 2 + rtl) * 4 + kt) * 64 + l];
#pragma unroll
    for (int cti = 0; cti < 2; cti++) {
      int ct = w * 4 + ch * 2 + cti;
      bf16x8 bf = *(const bf16x8*)(midT + (long)(b * 256 + 16 * ct + lr) * 128 + 32 * kt + 8 * lq);
#pragma unroll
      for (int rtl = 0; rtl < 2; rtl++)
        acc[rtl][cti] = __builtin_amdgcn_mfma_f32_16x16x32_bf16(af[rtl], bf, acc[rtl][cti], 0, 0, 0);
    }
  }
#pragma unroll
  for (int rtl = 0; rtl < 2; rtl++)
#pragma unroll
    for (int cti = 0; cti < 2; cti++) {
      int rt = rtp * 2 + rtl, ct = w * 4 + ch * 2 + cti;
#pragma unroll
      for (int r = 0; r < 4; r++)
        W3r[(long)(b * 128 + 16 * rt + 4 * lq + r) * 256 + 16 * ct + lr] = f2bf(acc[rtl][cti][r]);
    }
}

// G4: ATW = W3r[b] @ A_p; h_out = 0.1*ATW + 0.9*W1hA; out = sigmoid(Wfc.h_out)
__global__ __launch_bounds__(256, 2) void g4_kernel(char* __restrict__ ws,
    const float* __restrict__ Wfc, float* __restrict__ out)
{
  const unsigned short* W3r = (const unsigned short*)(ws + O_W3R);
  const unsigned short* Apk = (const unsigned short*)(ws + O_APK);
  const unsigned short* W1hAt = (const unsigned short*)(ws + O_W1HAT);
  int tid = threadIdx.x, w = tid >> 6, l = tid & 63, lr = l & 15, lq = l >> 4;
  int bi = blockIdx.x;
  int b = bi >> 2, cq = bi & 3;
  int ct = cq * 4 + w;
  f32x4 acc[8];
#pragma unroll
  for (int i = 0; i < 8; i++) acc[i] = (f32x4){0.f, 0.f, 0.f, 0.f};
  for (int kt = 0; kt < 8; kt++) {
    bf16x8 bfv = ((const bf16x8*)Apk)[(ct * 8 + kt) * 64 + l];
#pragma unroll
    for (int rt = 0; rt < 8; rt++) {
      bf16x8 af = *(const bf16x8*)(W3r + (long)(b * 128 + 16 * rt + lr) * 256 + 32 * kt + 8 * lq);
      acc[rt] = __builtin_amdgcn_mfma_f32_16x16x32_bf16(af, bfv, acc[rt], 0, 0, 0);
    }
  }
  float psum = 0.f;
#pragma unroll
  for (int rt = 0; rt < 8; rt++) {
    float4 wf = *(const float4*)(Wfc + 16 * rt + 4 * lq);
    u16x4 wv = *(const u16x4*)(W1hAt + (long)(b * 256 + 16 * ct + lr) * 128 + 16 * rt + 4 * lq);
    psum += wf.x * (0.1f * acc[rt][0] + 0.9f * bf2f(wv[0]));
    psum += wf.y * (0.1f * acc[rt][1] + 0.9f * bf2f(wv[1]));
    psum += wf.z * (0.1f * acc[rt][2] + 0.9f * bf2f(wv[2]));
    psum += wf.w * (0.1f * acc[rt][3] + 0.9f * bf2f(wv[3]));
  }
  psum += __shfl_xor(psum, 16);
  psum += __shfl_xor(psum, 32);
  if (lq == 0) out[b * 256 + ct * 16 + lr] = __builtin_amdgcn_rcpf(1.f + exp2f(-1.44269504f * psum));
}

// ---------------------------------------------------------------------------
extern "C" void kernel_launch(void* const* d_in, const int* in_sizes, int n_in,
                              void* d_out, int out_size, void* d_ws, size_t ws_size,
                              hipStream_t stream)
{
  const float* x    = (const float*)d_in[0];
  const float* A    = (const float*)d_in[1];
  const float* Wih0 = (const float*)d_in[2];
  const float* Whh0 = (const float*)d_in[3];
  const float* bih0 = (const float*)d_in[4];
  const float* bhh0 = (const float*)d_in[5];
  const float* Wih1 = (const float*)d_in[6];
  const float* Whh1 = (const float*)d_in[7];
  const float* bih1 = (const float*)d_in[8];
  const float* bhh1 = (const float*)d_in[9];
  const float* W1   = (const float*)d_in[10];
  const float* W2   = (const float*)d_in[11];
  const float* W3   = (const float*)d_in[12];
  const float* Wfc  = (const float*)d_in[13];
  char* ws = (char*)d_ws;

  prep_kernel<<<(PREP_TOT + 255) / 256, 256, 0, stream>>>(
      A, Wih0, Whh0, bih0, bhh0, Wih1, Whh1, bih1, bhh1, W1, W2, W3, ws);
  prepx_kernel<<<8192, 256, 0, stream>>>(x, ws);

  size_t need_full = (size_t)O_H1 + 134217728u;  // 8192-row h1
  size_t need_half = (size_t)O_H1 + 67108864u;   // 4096-row h1
  if (ws_size >= need_full) {
    lstm0_t<2><<<256, 512, 0, stream>>>(ws, 0);
    lstm1_t<2><<<256, 512, 0, stream>>>(ws, 0);
  } else if (ws_size >= need_half) {
    for (int c = 0; c < 2; c++) {
      lstm0_t<1><<<256, 512, 0, stream>>>(ws, c * 4096);
      lstm1_t<1><<<256, 512, 0, stream>>>(ws, c * 4096);
    }
  } else {
    for (int c = 0; c < 4; c++) {
      lstm0_t<1><<<128, 512, 0, stream>>>(ws, c * 2048);
      lstm1_t<1><<<128, 512, 0, stream>>>(ws, c * 2048);
    }
  }

  g1_kernel<<<256, 256, 0, stream>>>(ws);
  g2_kernel<<<256, 256, 0, stream>>>(ws);
  g3_kernel<<<256, 256, 0, stream>>>(ws);
  g4_kernel<<<128, 256, 0, stream>>>(ws, Wfc, (float*)d_out);
}

// Round 3
// 399.110 us; speedup vs baseline: 1.6816x; 1.2259x over previous
//
#include <hip/hip_runtime.h>

// ---------------------------------------------------------------------------
// 2-layer LSTM (BN=8192 seqs, T=64, F=16, H=128) + graph mixing stage.
// LSTM gates computed as G^T = W_packed . h^T  (A=weights in VGPR, B=h from LDS)
// Gate-row packing: gate-row gr = 16*rt + 4*ulocal + p  (p = gate i/f/g/o)
//   => D: lane l holds, in its 4 acc regs, gates i,f,g,o of
//      (data-row = l&15, unit = 4*rt + (l>>4)).  No cross-lane transpose.
// MFMA frag conventions (verified rounds 1-2):
//   A-frag: lane l holds A[16*rt + (l&15)][32*kt + 8*(l>>4) + i], i=0..7
//   B-frag: lane l holds B[32*kt + 8*(l>>4) + i][16*ct + (l&15)]
//   D:      lane l, reg r holds D[16*rt + 4*(l>>4) + r][16*ct + (l&15)]
// ---------------------------------------------------------------------------

typedef __attribute__((ext_vector_type(4))) float f32x4;
typedef __attribute__((ext_vector_type(8))) __bf16 bf16x8;
typedef __attribute__((ext_vector_type(8))) unsigned short u16x8;
typedef __attribute__((ext_vector_type(4))) unsigned short u16x4;

#define DEV static __device__ __forceinline__

DEV unsigned short f2bf(float f) {
  unsigned u = __builtin_bit_cast(unsigned, f);
  u = u + 0x7fffu + ((u >> 16) & 1u);
  return (unsigned short)(u >> 16);
}
DEV float bf2f(unsigned short s) {
  unsigned u = ((unsigned)s) << 16;
  return __builtin_bit_cast(float, u);
}

// LSTM cell, gates g[0..3] = i,f,g,o. 5 exp2 + 3 rcp.
// sig(a)*tanh(b) = (e^{2b}-1) / ((e^{2b}+1)*(1+e^{-a}))
DEV float cell2(const f32x4 g, float& c) {
  const float K1 = 1.44269504f, K2 = 2.88539008f;
  float t1 = exp2f(K2 * g[2]);     // e^{2g}
  float t2 = exp2f(-K1 * g[0]);    // e^{-i}
  float ef = exp2f(-K1 * g[1]);    // e^{-f}
  float d1 = t1 + 1.f;
  float den1 = fmaf(d1, t2, d1);
  float it = (t1 - 1.f) * __builtin_amdgcn_rcpf(den1);   // sig(i)*tanh(g)
  c = __builtin_amdgcn_rcpf(1.f + ef) * c + it;
  float t3 = exp2f(K2 * c);        // e^{2c}
  float t4 = exp2f(-K1 * g[3]);    // e^{-o}
  float d3 = t3 + 1.f;
  float den3 = fmaf(d3, t4, d3);
  return (t3 - 1.f) * __builtin_amdgcn_rcpf(den3);       // sig(o)*tanh(c)
}

// ---------------- workspace layout (bytes) ----------------
#define O_W0PK   0            // 32rt*5kt*64l*8i bf16 = 163840
#define O_W1PK   163840       // 32rt*8kt*64l*8i bf16 = 262144
#define O_APK    425984       // 131072
#define O_W1APK  557056       // 32768
#define O_W2APK  589824       // 32768
#define O_W3APK  622592       // 32768
#define O_BIAS0  655360       // 2048
#define O_BIAS1  657408       // 2048
#define O_HTT    659456       // 2097152  hT^T [32][128][256] bf16
#define O_HAT    2756608      // 2097152
#define O_MIDT   4853760      // 2097152
#define O_W1HAT  6950912      // 2097152
#define O_W3R    9048064      // 2097152
#define O_XPK    11145216     // 33554432 x B-frags (padded K=32)
#define O_H1     44699648     // up to 128 MiB h1 [row][t][128] bf16

#define PREP_TOT 328704

// ---------------- prepass: pack weights -----------------------------------
__global__ void prep_kernel(const float* __restrict__ A,
    const float* __restrict__ Wih0, const float* __restrict__ Whh0,
    const float* __restrict__ bih0, const float* __restrict__ bhh0,
    const float* __restrict__ Wih1, const float* __restrict__ Whh1,
    const float* __restrict__ bih1, const float* __restrict__ bhh1,
    const float* __restrict__ W1, const float* __restrict__ W2,
    const float* __restrict__ W3, char* __restrict__ ws)
{
  int idx = blockIdx.x * blockDim.x + threadIdx.x;
  if (idx >= PREP_TOT) return;
  if (idx < 81920) {                       // W0pk A-frags: gr = 16rt+4u_loc+p
    int o = idx, i = o & 7, l = (o >> 3) & 63, f = o >> 9;
    int kt = f % 5, rt = f / 5;
    int lr = l & 15, lq = l >> 4;
    int gc = (lr & 3) * 128 + 4 * rt + (lr >> 2);   // gate p, unit u
    float v;
    if (kt < 4) v = Whh0[gc * 128 + 32 * kt + 8 * lq + i];
    else { int kk = 8 * lq + i; v = (kk < 16) ? Wih0[gc * 16 + kk] : 0.f; }
    ((unsigned short*)(ws + O_W0PK))[idx] = f2bf(v);
  } else if (idx < 212992) {               // W1pk: kt<4 = h1-input, kt>=4 = recurrent
    int o = idx - 81920, i = o & 7, l = (o >> 3) & 63, f = o >> 9;
    int kt = f & 7, rt = f >> 3;
    int lr = l & 15, lq = l >> 4;
    int gc = (lr & 3) * 128 + 4 * rt + (lr >> 2);
    float v = (kt < 4) ? Wih1[gc * 128 + 32 * kt + 8 * lq + i]
                       : Whh1[gc * 128 + 32 * (kt - 4) + 8 * lq + i];
    ((unsigned short*)(ws + O_W1PK))[o] = f2bf(v);
  } else if (idx < 278528) {               // Apk = sigmoid(A) B-frags
    int o = idx - 212992, i = o & 7, l = (o >> 3) & 63, f = o >> 9;
    int kt = f & 7, ct = f >> 3;
    int n = 32 * kt + 8 * (l >> 4) + i;
    int lc = 16 * ct + (l & 15);
    float e = exp2f(-1.44269504f * A[n * 256 + lc]);
    ((unsigned short*)(ws + O_APK))[o] = f2bf(__builtin_amdgcn_rcpf(1.f + e));
  } else if (idx < 327680) {               // W1/W2/W3 A-frags (graph stage)
    int o = idx - 278528;
    int m = o >> 14;
    int oo = o & 16383;
    int i = oo & 7, l = (oo >> 3) & 63, f = oo >> 9;
    int kt = f & 3, rt = f >> 2;
    int g = 16 * rt + (l & 15);
    int k = 32 * kt + 8 * (l >> 4) + i;
    const float* W = (m == 0) ? W1 : (m == 1) ? W2 : W3;
    unsigned short* dst = (unsigned short*)(ws + ((m == 0) ? O_W1APK : (m == 1) ? O_W2APK : O_W3APK));
    dst[oo] = f2bf(W[g * 128 + k]);
  } else if (idx < 328192) {
    int c = idx - 327680;
    ((float*)(ws + O_BIAS0))[c] = bih0[c] + bhh0[c];
  } else {
    int c = idx - 328192;
    ((float*)(ws + O_BIAS1))[c] = bih1[c] + bhh1[c];
  }
}

// x -> padded B-frag bf16: lane l holds x[16rt+(l&15)][8*(l>>4)+i] (zero lq>=2)
__global__ void prepx_kernel(const float* __restrict__ x, char* __restrict__ ws)
{
  int tid = blockIdx.x * 256 + threadIdx.x;     // 0 .. 2097151
  int dat = (tid < 1048576) ? 1 : 0;
  int id = tid & 1048575;
  int half = id & 1, t = (id >> 1) & 63, row = id >> 7;
  u16x8 v = (u16x8)0;
  if (dat) {
    const float* p = x + ((long)row * 64 + t) * 16 + 8 * half;
    float4 a = *(const float4*)p;
    float4 b = *(const float4*)(p + 4);
    v[0] = f2bf(a.x); v[1] = f2bf(a.y); v[2] = f2bf(a.z); v[3] = f2bf(a.w);
    v[4] = f2bf(b.x); v[5] = f2bf(b.y); v[6] = f2bf(b.z); v[7] = f2bf(b.w);
  }
  int lane = (dat ? 0 : 32) + half * 16 + (row & 15);
  int rt = row >> 4;
  ((u16x8*)(ws + O_XPK))[(rt * 64 + t) * 64 + lane] = v;
}

// ---------------- LSTM layer 0: 32 rows/block, 16 waves, 1 barrier/step ----
__global__ __launch_bounds__(1024, 4) void lstm0_k(char* __restrict__ ws, int row_base)
{
  const unsigned short* W0pk = (const unsigned short*)(ws + O_W0PK);
  const float* bias0 = (const float*)(ws + O_BIAS0);
  const unsigned short* xpk = (const unsigned short*)(ws + O_XPK);
  unsigned short* h1 = (unsigned short*)(ws + O_H1);

  int tid = threadIdx.x;
  int W = tid >> 6, l = tid & 63, lr = l & 15, lq = l >> 4;
  int lrow = blockIdx.x * 32;              // chunk-local row base
  long grow0 = (long)row_base + lrow;

  __shared__ unsigned char hlds[2][8192];  // h state [32 rows][128 u] swizzled
  ((unsigned long long*)hlds[0])[tid] = 0ull;

  bf16x8 Af[2][5];                          // rt = 2W+s
#pragma unroll
  for (int s = 0; s < 2; s++)
#pragma unroll
    for (int kt = 0; kt < 5; kt++)
      Af[s][kt] = ((const bf16x8*)W0pk)[(((2 * W + s) * 5) + kt) * 64 + l];

  f32x4 bias_c[2];
#pragma unroll
  for (int s = 0; s < 2; s++)
#pragma unroll
    for (int r = 0; r < 4; r++)
      bias_c[s][r] = bias0[r * 128 + 4 * (2 * W + s) + lq];

  float c_st[2][2] = {{0.f, 0.f}, {0.f, 0.f}};  // [ct][s]

  int rd[2][4], wh[2][2];
#pragma unroll
  for (int ct = 0; ct < 2; ct++) {
#pragma unroll
    for (int kt = 0; kt < 4; kt++)
      rd[ct][kt] = (16 * ct + lr) * 256 + ((64 * kt + 16 * lq) ^ ((lr & 7) << 4));
#pragma unroll
    for (int s = 0; s < 2; s++) {
      int u = 4 * (2 * W + s) + lq;
      wh[ct][s] = (16 * ct + lr) * 256 + ((2 * u) ^ ((lr & 7) << 4));
    }
  }
  long rtg = grow0 >> 4;
  __syncthreads();

  for (int t = 0; t < 64; t++) {
    const unsigned char* rbuf = hlds[t & 1];
    unsigned char* wbuf = hlds[(t & 1) ^ 1];
#pragma unroll
    for (int ct = 0; ct < 2; ct++) {
      f32x4 acc[2];
      acc[0] = bias_c[0]; acc[1] = bias_c[1];
#pragma unroll
      for (int kt = 0; kt < 4; kt++) {
        bf16x8 hb = *(const bf16x8*)(rbuf + rd[ct][kt]);
        acc[0] = __builtin_amdgcn_mfma_f32_16x16x32_bf16(Af[0][kt], hb, acc[0], 0, 0, 0);
        acc[1] = __builtin_amdgcn_mfma_f32_16x16x32_bf16(Af[1][kt], hb, acc[1], 0, 0, 0);
      }
      bf16x8 xb = ((const bf16x8*)xpk)[((rtg + ct) * 64 + t) * 64 + l];
      acc[0] = __builtin_amdgcn_mfma_f32_16x16x32_bf16(Af[0][4], xb, acc[0], 0, 0, 0);
      acc[1] = __builtin_amdgcn_mfma_f32_16x16x32_bf16(Af[1][4], xb, acc[1], 0, 0, 0);
#pragma unroll
      for (int s = 0; s < 2; s++) {
        float h = cell2(acc[s], c_st[ct][s]);
        unsigned short hb16 = f2bf(h);
        *(unsigned short*)(wbuf + wh[ct][s]) = hb16;
        int u = 4 * (2 * W + s) + lq;
        h1[((long)(lrow + 16 * ct + lr) * 64 + t) * 128 + u] = hb16;
      }
    }
    __syncthreads();
  }
}

// ---------------- LSTM layer 1: 16 rows/block, 16 waves --------------------
__global__ __launch_bounds__(1024, 4) void lstm1_k(char* __restrict__ ws, int row_base)
{
  const unsigned short* W1pk = (const unsigned short*)(ws + O_W1PK);
  const float* bias1 = (const float*)(ws + O_BIAS1);
  const unsigned short* h1 = (const unsigned short*)(ws + O_H1);
  unsigned short* hTt = (unsigned short*)(ws + O_HTT);

  int tid = threadIdx.x;
  int W = tid >> 6, l = tid & 63, lr = l & 15, lq = l >> 4;
  int lrow = blockIdx.x * 16;
  long grow0 = (long)row_base + lrow;

  __shared__ unsigned char hlds[2][4096];  // h1-layer state
  __shared__ unsigned char h1s[2][4096];   // staged h1 input
  ((unsigned int*)hlds[0])[tid] = 0u;

  // h1 staging: each thread owns (prow = tid>>6, unit-pair c = tid&63)
  int prow = tid >> 6, pc = tid & 63;
  const unsigned short* h1src = h1 + ((long)(lrow + prow) * 64) * 128 + 2 * pc;
  int h1dst = prow * 256 + ((4 * pc) ^ ((prow & 7) << 4));
  *(unsigned int*)(h1s[0] + h1dst) = *(const unsigned int*)h1src;  // t=0

  bf16x8 Af[2][8];
#pragma unroll
  for (int s = 0; s < 2; s++)
#pragma unroll
    for (int kt = 0; kt < 8; kt++)
      Af[s][kt] = ((const bf16x8*)W1pk)[(((2 * W + s) * 8) + kt) * 64 + l];

  f32x4 bias_c[2];
#pragma unroll
  for (int s = 0; s < 2; s++)
#pragma unroll
    for (int r = 0; r < 4; r++)
      bias_c[s][r] = bias1[r * 128 + 4 * (2 * W + s) + lq];

  float c_st[2] = {0.f, 0.f};

  int rd[4], wh[2];
#pragma unroll
  for (int kt = 0; kt < 4; kt++)
    rd[kt] = lr * 256 + ((64 * kt + 16 * lq) ^ ((lr & 7) << 4));
#pragma unroll
  for (int s = 0; s < 2; s++) {
    int u = 4 * (2 * W + s) + lq;
    wh[s] = lr * 256 + ((2 * u) ^ ((lr & 7) << 4));
  }
  __syncthreads();

  for (int t = 0; t < 64; t++) {
    const unsigned char* rbuf = hlds[t & 1];
    unsigned char* wbuf = hlds[(t & 1) ^ 1];
    const unsigned char* h1r = h1s[t & 1];
    unsigned char* h1w = h1s[(t & 1) ^ 1];
    // prefetch next h1 tile (issue early, write late)
    int tn = (t + 1) & 63;
    unsigned int pf = *(const unsigned int*)(h1src + tn * 128);

    f32x4 acc[2];
    acc[0] = bias_c[0]; acc[1] = bias_c[1];
#pragma unroll
    for (int kt = 0; kt < 4; kt++) {
      bf16x8 xb = *(const bf16x8*)(h1r + rd[kt]);
      acc[0] = __builtin_amdgcn_mfma_f32_16x16x32_bf16(Af[0][kt], xb, acc[0], 0, 0, 0);
      acc[1] = __builtin_amdgcn_mfma_f32_16x16x32_bf16(Af[1][kt], xb, acc[1], 0, 0, 0);
    }
#pragma unroll
    for (int kt = 0; kt < 4; kt++) {
      bf16x8 hb = *(const bf16x8*)(rbuf + rd[kt]);
      acc[0] = __builtin_amdgcn_mfma_f32_16x16x32_bf16(Af[0][4 + kt], hb, acc[0], 0, 0, 0);
      acc[1] = __builtin_amdgcn_mfma_f32_16x16x32_bf16(Af[1][4 + kt], hb, acc[1], 0, 0, 0);
    }
#pragma unroll
    for (int s = 0; s < 2; s++) {
      float h = cell2(acc[s], c_st[s]);
      unsigned short hb16 = f2bf(h);
      *(unsigned short*)(wbuf + wh[s]) = hb16;
      if (t == 63) {
        long grow = grow0 + lr;
        int u = 4 * (2 * W + s) + lq;
        hTt[((grow >> 8) * 128 + u) * 256 + (grow & 255)] = hb16;
      }
    }
    *(unsigned int*)(h1w + h1dst) = pf;
    __syncthreads();
  }
}

// ---------------- graph stage (unchanged, verified) ------------------------
__global__ __launch_bounds__(256, 2) void g1_kernel(char* __restrict__ ws)
{
  const unsigned short* hTt = (const unsigned short*)(ws + O_HTT);
  const unsigned short* Apk = (const unsigned short*)(ws + O_APK);
  unsigned short* HAt = (unsigned short*)(ws + O_HAT);
  int tid = threadIdx.x, w = tid >> 6, l = tid & 63, lr = l & 15, lq = l >> 4;
  int bi = blockIdx.x;
  int b = bi >> 3, rtp = (bi >> 1) & 3, ch = bi & 1;
  f32x4 acc[2][2];
#pragma unroll
  for (int i = 0; i < 2; i++)
#pragma unroll
    for (int j = 0; j < 2; j++) acc[i][j] = (f32x4){0.f, 0.f, 0.f, 0.f};
  for (int kt = 0; kt < 8; kt++) {
    bf16x8 af[2];
#pragma unroll
    for (int rtl = 0; rtl < 2; rtl++) {
      int rt = rtp * 2 + rtl;
      af[rtl] = *(const bf16x8*)(hTt + (long)(b * 128 + 16 * rt + lr) * 256 + 32 * kt + 8 * lq);
    }
#pragma unroll
    for (int cti = 0; cti < 2; cti++) {
      int ct = w * 4 + ch * 2 + cti;
      bf16x8 bf = ((const bf16x8*)Apk)[(ct * 8 + kt) * 64 + l];
#pragma unroll
      for (int rtl = 0; rtl < 2; rtl++)
        acc[rtl][cti] = __builtin_amdgcn_mfma_f32_16x16x32_bf16(af[rtl], bf, acc[rtl][cti], 0, 0, 0);
    }
  }
#pragma unroll
  for (int rtl = 0; rtl < 2; rtl++)
#pragma unroll
    for (int cti = 0; cti < 2; cti++) {
      int rt = rtp * 2 + rtl, ct = w * 4 + ch * 2 + cti;
      u16x4 pk;
#pragma unroll
      for (int r = 0; r < 4; r++) pk[r] = f2bf(acc[rtl][cti][r]);
      *(u16x4*)(HAt + (long)(b * 256 + 16 * ct + lr) * 128 + 16 * rt + 4 * lq) = pk;
    }
}

__global__ __launch_bounds__(256, 2) void g2_kernel(char* __restrict__ ws)
{
  const unsigned short* HAt = (const unsigned short*)(ws + O_HAT);
  const unsigned short* W1apk = (const unsigned short*)(ws + O_W1APK);
  const unsigned short* W2apk = (const unsigned short*)(ws + O_W2APK);
  unsigned short* W1hAt = (unsigned short*)(ws + O_W1HAT);
  unsigned short* midT = (unsigned short*)(ws + O_MIDT);
  int tid = threadIdx.x, w = tid >> 6, l = tid & 63, lr = l & 15, lq = l >> 4;
  int bi = blockIdx.x;
  int b = bi >> 3, rtp = (bi >> 1) & 3, ch = bi & 1;
  f32x4 a1[2][2], a2[2][2];
#pragma unroll
  for (int i = 0; i < 2; i++)
#pragma unroll
    for (int j = 0; j < 2; j++) { a1[i][j] = (f32x4){0.f,0.f,0.f,0.f}; a2[i][j] = (f32x4){0.f,0.f,0.f,0.f}; }
  for (int kt = 0; kt < 4; kt++) {
    bf16x8 af1[2], af2[2];
#pragma unroll
    for (int rtl = 0; rtl < 2; rtl++) {
      int rt = rtp * 2 + rtl;
      af1[rtl] = ((const bf16x8*)W1apk)[(rt * 4 + kt) * 64 + l];
      af2[rtl] = ((const bf16x8*)W2apk)[(rt * 4 + kt) * 64 + l];
    }
#pragma unroll
    for (int cti = 0; cti < 2; cti++) {
      int ct = w * 4 + ch * 2 + cti;
      bf16x8 bf = *(const bf16x8*)(HAt + (long)(b * 256 + 16 * ct + lr) * 128 + 32 * kt + 8 * lq);
#pragma unroll
      for (int rtl = 0; rtl < 2; rtl++) {
        a1[rtl][cti] = __builtin_amdgcn_mfma_f32_16x16x32_bf16(af1[rtl], bf, a1[rtl][cti], 0, 0, 0);
        a2[rtl][cti] = __builtin_amdgcn_mfma_f32_16x16x32_bf16(af2[rtl], bf, a2[rtl][cti], 0, 0, 0);
      }
    }
  }
#pragma unroll
  for (int rtl = 0; rtl < 2; rtl++)
#pragma unroll
    for (int cti = 0; cti < 2; cti++) {
      int rt = rtp * 2 + rtl, ct = w * 4 + ch * 2 + cti;
      u16x4 p1, p2;
#pragma unroll
      for (int r = 0; r < 4; r++) {
        p1[r] = f2bf(a1[rtl][cti][r]);
        p2[r] = f2bf(fmaxf(a2[rtl][cti][r], 0.f));
      }
      long off = (long)(b * 256 + 16 * ct + lr) * 128 + 16 * rt + 4 * lq;
      *(u16x4*)(W1hAt + off) = p1;
      *(u16x4*)(midT + off) = p2;
    }
}

__global__ __launch_bounds__(256, 2) void g3_kernel(char* __restrict__ ws)
{
  const unsigned short* midT = (const unsigned short*)(ws + O_MIDT);
  const unsigned short* W3apk = (const unsigned short*)(ws + O_W3APK);
  unsigned short* W3r = (unsigned short*)(ws + O_W3R);
  int tid = threadIdx.x, w = tid >> 6, l = tid & 63, lr = l & 15, lq = l >> 4;
  int bi = blockIdx.x;
  int b = bi >> 3, rtp = (bi >> 1) & 3, ch = bi & 1;
  f32x4 acc[2][2];
#pragma unroll
  for (int i = 0; i < 2; i++)
#pragma unroll
    for (int j = 0; j < 2; j++) acc[i][j] = (f32x4){0.f, 0.f, 0.f, 0.f};
  for (int kt = 0; kt < 4; kt++) {
    bf16x8 af[2];
#pragma unroll
    for (int rtl = 0; rtl < 2; rtl++)
      af[rtl] = ((const bf16x8*)W3apk)[((rtp * 2 + rtl) * 4 + kt) * 64 + l];
#pragma unroll
    for (int cti = 0; cti < 2; cti++) {
      int ct = w * 4 + ch * 2 + cti;
      bf16x8 bf = *(const bf16x8*)(midT + (long)(b * 256 + 16 * ct + lr) * 128 + 32 * kt + 8 * lq);
#pragma unroll
      for (int rtl = 0; rtl < 2; rtl++)
        acc[rtl][cti] = __builtin_amdgcn_mfma_f32_16x16x32_bf16(af[rtl], bf, acc[rtl][cti], 0, 0, 0);
    }
  }
#pragma unroll
  for (int rtl = 0; rtl < 2; rtl++)
#pragma unroll
    for (int cti = 0; cti < 2; cti++) {
      int rt = rtp * 2 + rtl, ct = w * 4 + ch * 2 + cti;
#pragma unroll
      for (int r = 0; r < 4; r++)
        W3r[(long)(b * 128 + 16 * rt + 4 * lq + r) * 256 + 16 * ct + lr] = f2bf(acc[rtl][cti][r]);
    }
}

__global__ __launch_bounds__(256, 2) void g4_kernel(char* __restrict__ ws,
    const float* __restrict__ Wfc, float* __restrict__ out)
{
  const unsigned short* W3r = (const unsigned short*)(ws + O_W3R);
  const unsigned short* Apk = (const unsigned short*)(ws + O_APK);
  const unsigned short* W1hAt = (const unsigned short*)(ws + O_W1HAT);
  int tid = threadIdx.x, w = tid >> 6, l = tid & 63, lr = l & 15, lq = l >> 4;
  int bi = blockIdx.x;
  int b = bi >> 2, cq = bi & 3;
  int ct = cq * 4 + w;
  f32x4 acc[8];
#pragma unroll
  for (int i = 0; i < 8; i++) acc[i] = (f32x4){0.f, 0.f, 0.f, 0.f};
  for (int kt = 0; kt < 8; kt++) {
    bf16x8 bfv = ((const bf16x8*)Apk)[(ct * 8 + kt) * 64 + l];
#pragma unroll
    for (int rt = 0; rt < 8; rt++) {
      bf16x8 af = *(const bf16x8*)(W3r + (long)(b * 128 + 16 * rt + lr) * 256 + 32 * kt + 8 * lq);
      acc[rt] = __builtin_amdgcn_mfma_f32_16x16x32_bf16(af, bfv, acc[rt], 0, 0, 0);
    }
  }
  float psum = 0.f;
#pragma unroll
  for (int rt = 0; rt < 8; rt++) {
    float4 wf = *(const float4*)(Wfc + 16 * rt + 4 * lq);
    u16x4 wv = *(const u16x4*)(W1hAt + (long)(b * 256 + 16 * ct + lr) * 128 + 16 * rt + 4 * lq);
    psum += wf.x * (0.1f * acc[rt][0] + 0.9f * bf2f(wv[0]));
    psum += wf.y * (0.1f * acc[rt][1] + 0.9f * bf2f(wv[1]));
    psum += wf.z * (0.1f * acc[rt][2] + 0.9f * bf2f(wv[2]));
    psum += wf.w * (0.1f * acc[rt][3] + 0.9f * bf2f(wv[3]));
  }
  psum += __shfl_xor(psum, 16);
  psum += __shfl_xor(psum, 32);
  if (lq == 0) out[b * 256 + ct * 16 + lr] = __builtin_amdgcn_rcpf(1.f + exp2f(-1.44269504f * psum));
}

// ---------------------------------------------------------------------------
extern "C" void kernel_launch(void* const* d_in, const int* in_sizes, int n_in,
                              void* d_out, int out_size, void* d_ws, size_t ws_size,
                              hipStream_t stream)
{
  const float* x    = (const float*)d_in[0];
  const float* A    = (const float*)d_in[1];
  const float* Wih0 = (const float*)d_in[2];
  const float* Whh0 = (const float*)d_in[3];
  const float* bih0 = (const float*)d_in[4];
  const float* bhh0 = (const float*)d_in[5];
  const float* Wih1 = (const float*)d_in[6];
  const float* Whh1 = (const float*)d_in[7];
  const float* bih1 = (const float*)d_in[8];
  const float* bhh1 = (const float*)d_in[9];
  const float* W1   = (const float*)d_in[10];
  const float* W2   = (const float*)d_in[11];
  const float* W3   = (const float*)d_in[12];
  const float* Wfc  = (const float*)d_in[13];
  char* ws = (char*)d_ws;

  prep_kernel<<<(PREP_TOT + 255) / 256, 256, 0, stream>>>(
      A, Wih0, Whh0, bih0, bhh0, Wih1, Whh1, bih1, bhh1, W1, W2, W3, ws);
  prepx_kernel<<<8192, 256, 0, stream>>>(x, ws);

  size_t need_full = (size_t)O_H1 + 134217728u;  // 8192-row h1
  size_t need_half = (size_t)O_H1 + 67108864u;   // 4096-row h1
  if (ws_size >= need_full) {
    lstm0_k<<<256, 1024, 0, stream>>>(ws, 0);
    lstm1_k<<<512, 1024, 0, stream>>>(ws, 0);
  } else if (ws_size >= need_half) {
    for (int c = 0; c < 2; c++) {
      lstm0_k<<<128, 1024, 0, stream>>>(ws, c * 4096);
      lstm1_k<<<256, 1024, 0, stream>>>(ws, c * 4096);
    }
  } else {
    for (int c = 0; c < 4; c++) {
      lstm0_k<<<64, 1024, 0, stream>>>(ws, c * 2048);
      lstm1_k<<<128, 1024, 0, stream>>>(ws, c * 2048);
    }
  }

  g1_kernel<<<256, 256, 0, stream>>>(ws);
  g2_kernel<<<256, 256, 0, stream>>>(ws);
  g3_kernel<<<256, 256, 0, stream>>>(ws);
  g4_kernel<<<128, 256, 0, stream>>>(ws, Wfc, (float*)d_out);
}

// Round 4
// 357.692 us; speedup vs baseline: 1.8763x; 1.1158x over previous
//
#include <hip/hip_runtime.h>

// ---------------------------------------------------------------------------
// 2-layer LSTM (BN=8192 seqs, T=64, F=16, H=128) + graph mixing stage.
// LSTM gates computed as G^T = W_packed . h^T  (A=weights in VGPR, B=h from LDS)
// Gate-row packing: gate-row gr = 16*rt + 4*ulocal + p  (p = gate i/f/g/o)
//   => D: lane l holds, in its 4 acc regs, gates i,f,g,o of
//      (data-row = l&15, unit = 4*rt + (l>>4)).  No cross-lane transpose.
// MFMA frag conventions (verified rounds 1-3):
//   A-frag: lane l holds A[16*rt + (l&15)][32*kt + 8*(l>>4) + i], i=0..7
//   B-frag: lane l holds B[32*kt + 8*(l>>4) + i][16*ct + (l&15)]
//   D:      lane l, reg r holds D[16*rt + 4*(l>>4) + r][16*ct + (l&15)]
// ---------------------------------------------------------------------------

typedef __attribute__((ext_vector_type(4))) float f32x4;
typedef __attribute__((ext_vector_type(8))) __bf16 bf16x8;
typedef __attribute__((ext_vector_type(8))) unsigned short u16x8;
typedef __attribute__((ext_vector_type(4))) unsigned short u16x4;

#define DEV static __device__ __forceinline__

DEV unsigned short f2bf(float f) {
  unsigned u = __builtin_bit_cast(unsigned, f);
  u = u + 0x7fffu + ((u >> 16) & 1u);
  return (unsigned short)(u >> 16);
}
DEV float bf2f(unsigned short s) {
  unsigned u = ((unsigned)s) << 16;
  return __builtin_bit_cast(float, u);
}

// LSTM cell, gates g[0..3] = i,f,g,o. 5 exp2 + 3 rcp.
// sig(a)*tanh(b) = (e^{2b}-1) / ((e^{2b}+1)*(1+e^{-a}))
DEV float cell2(const f32x4 g, float& c) {
  const float K1 = 1.44269504f, K2 = 2.88539008f;
  float t1 = exp2f(K2 * g[2]);     // e^{2g}
  float t2 = exp2f(-K1 * g[0]);    // e^{-i}
  float ef = exp2f(-K1 * g[1]);    // e^{-f}
  float d1 = t1 + 1.f;
  float den1 = fmaf(d1, t2, d1);
  float it = (t1 - 1.f) * __builtin_amdgcn_rcpf(den1);   // sig(i)*tanh(g)
  c = __builtin_amdgcn_rcpf(1.f + ef) * c + it;
  float t3 = exp2f(K2 * c);        // e^{2c}
  float t4 = exp2f(-K1 * g[3]);    // e^{-o}
  float d3 = t3 + 1.f;
  float den3 = fmaf(d3, t4, d3);
  return (t3 - 1.f) * __builtin_amdgcn_rcpf(den3);       // sig(o)*tanh(c)
}

// ---------------- workspace layout (bytes) ----------------
#define O_W0PK   0            // 32rt*5kt*64l*8i bf16 = 163840
#define O_W1PK   163840       // 32rt*8kt*64l*8i bf16 = 262144
#define O_APK    425984       // 131072
#define O_W1APK  557056       // 32768
#define O_W2APK  589824       // 32768
#define O_W3APK  622592       // 32768
#define O_BIAS0  655360       // 2048
#define O_BIAS1  657408       // 2048
#define O_HTT    659456       // 2097152  hT^T [32][128][256] bf16
#define O_HAT    2756608      // 2097152
#define O_MIDT   4853760      // 2097152
#define O_W1HAT  6950912      // 2097152
#define O_W3R    9048064      // 2097152
#define O_XPK    11145216     // 33554432 x B-frags (padded K=32, pad col16=1.0)
#define O_H1     44699648     // up to 128 MiB h1 [row][t][128] bf16

#define PREP_TOT 328704

// ---------------- prepass: pack weights -----------------------------------
__global__ void prep_kernel(const float* __restrict__ A,
    const float* __restrict__ Wih0, const float* __restrict__ Whh0,
    const float* __restrict__ bih0, const float* __restrict__ bhh0,
    const float* __restrict__ Wih1, const float* __restrict__ Whh1,
    const float* __restrict__ bih1, const float* __restrict__ bhh1,
    const float* __restrict__ W1, const float* __restrict__ W2,
    const float* __restrict__ W3, char* __restrict__ ws)
{
  int idx = blockIdx.x * blockDim.x + threadIdx.x;
  if (idx >= PREP_TOT) return;
  if (idx < 81920) {                       // W0pk A-frags: gr = 16rt+4u_loc+p
    int o = idx, i = o & 7, l = (o >> 3) & 63, f = o >> 9;
    int kt = f % 5, rt = f / 5;
    int lr = l & 15, lq = l >> 4;
    int gc = (lr & 3) * 128 + 4 * rt + (lr >> 2);   // gate p, unit u
    float v;
    if (kt < 4) v = Whh0[gc * 128 + 32 * kt + 8 * lq + i];
    else {
      int kk = 8 * lq + i;
      v = (kk < 16) ? Wih0[gc * 16 + kk]
                    : (kk == 16 ? (bih0[gc] + bhh0[gc]) : 0.f);  // bias row
    }
    ((unsigned short*)(ws + O_W0PK))[idx] = f2bf(v);
  } else if (idx < 212992) {               // W1pk: kt<4 = h1-input, kt>=4 = recurrent
    int o = idx - 81920, i = o & 7, l = (o >> 3) & 63, f = o >> 9;
    int kt = f & 7, rt = f >> 3;
    int lr = l & 15, lq = l >> 4;
    int gc = (lr & 3) * 128 + 4 * rt + (lr >> 2);
    float v = (kt < 4) ? Wih1[gc * 128 + 32 * kt + 8 * lq + i]
                       : Whh1[gc * 128 + 32 * (kt - 4) + 8 * lq + i];
    ((unsigned short*)(ws + O_W1PK))[o] = f2bf(v);
  } else if (idx < 278528) {               // Apk = sigmoid(A) B-frags
    int o = idx - 212992, i = o & 7, l = (o >> 3) & 63, f = o >> 9;
    int kt = f & 7, ct = f >> 3;
    int n = 32 * kt + 8 * (l >> 4) + i;
    int lc = 16 * ct + (l & 15);
    float e = exp2f(-1.44269504f * A[n * 256 + lc]);
    ((unsigned short*)(ws + O_APK))[o] = f2bf(__builtin_amdgcn_rcpf(1.f + e));
  } else if (idx < 327680) {               // W1/W2/W3 A-frags (graph stage)
    int o = idx - 278528;
    int m = o >> 14;
    int oo = o & 16383;
    int i = oo & 7, l = (oo >> 3) & 63, f = oo >> 9;
    int kt = f & 3, rt = f >> 2;
    int g = 16 * rt + (l & 15);
    int k = 32 * kt + 8 * (l >> 4) + i;
    const float* W = (m == 0) ? W1 : (m == 1) ? W2 : W3;
    unsigned short* dst = (unsigned short*)(ws + ((m == 0) ? O_W1APK : (m == 1) ? O_W2APK : O_W3APK));
    dst[oo] = f2bf(W[g * 128 + k]);
  } else if (idx < 328192) {
    int c = idx - 327680;
    ((float*)(ws + O_BIAS0))[c] = bih0[c] + bhh0[c];
  } else {
    int c = idx - 328192;
    ((float*)(ws + O_BIAS1))[c] = bih1[c] + bhh1[c];
  }
}

// x -> padded B-frag bf16: lane l holds x[16rt+(l&15)][8*(l>>4)+i]
// pad column k=16 = 1.0 (bias row multiplier), k>16 = 0.
__global__ void prepx_kernel(const float* __restrict__ x, char* __restrict__ ws)
{
  int tid = blockIdx.x * 256 + threadIdx.x;     // 0 .. 2097151
  int dat = (tid < 1048576) ? 1 : 0;
  int id = tid & 1048575;
  int half = id & 1, t = (id >> 1) & 63, row = id >> 7;
  u16x8 v = (u16x8)0;
  if (dat) {
    const float* p = x + ((long)row * 64 + t) * 16 + 8 * half;
    float4 a = *(const float4*)p;
    float4 b = *(const float4*)(p + 4);
    v[0] = f2bf(a.x); v[1] = f2bf(a.y); v[2] = f2bf(a.z); v[3] = f2bf(a.w);
    v[4] = f2bf(b.x); v[5] = f2bf(b.y); v[6] = f2bf(b.z); v[7] = f2bf(b.w);
  } else if (half == 0) {
    v[0] = 0x3F80;                              // k=16 -> 1.0f (bias column)
  }
  int lane = (dat ? 0 : 32) + half * 16 + (row & 15);
  int rt = row >> 4;
  ((u16x8*)(ws + O_XPK))[(rt * 64 + t) * 64 + lane] = v;
}

// ---------------- LSTM layer 0: 16 rows/block, 16 waves, 1 barrier/step ----
// Bias folded into K-pad column; x prefetched 1 step ahead;
// h1 written via LDS bounce -> fully coalesced u32 stores.
__global__ __launch_bounds__(1024, 4) void lstm0_k(char* __restrict__ ws, int row_base)
{
  const unsigned short* W0pk = (const unsigned short*)(ws + O_W0PK);
  const unsigned short* xpk = (const unsigned short*)(ws + O_XPK);
  unsigned short* h1 = (unsigned short*)(ws + O_H1);

  int tid = threadIdx.x;
  int Wv = tid >> 6, l = tid & 63, lr = l & 15, lq = l >> 4;
  int lrow = blockIdx.x * 16;
  long grow0 = (long)row_base + lrow;

  __shared__ unsigned char hlds[2][4096];  // h state [16 rows][128 u] swizzled
  ((unsigned int*)hlds[0])[tid] = 0u;

  bf16x8 Af[2][5];                          // A-tiles rt = 2Wv+s
#pragma unroll
  for (int s = 0; s < 2; s++)
#pragma unroll
    for (int kt = 0; kt < 5; kt++)
      Af[s][kt] = ((const bf16x8*)W0pk)[(((2 * Wv + s) * 5) + kt) * 64 + l];

  float c_st[2] = {0.f, 0.f};

  int rd[4], wh[2];
#pragma unroll
  for (int kt = 0; kt < 4; kt++)
    rd[kt] = lr * 256 + ((64 * kt + 16 * lq) ^ ((lr & 7) << 4));
#pragma unroll
  for (int s = 0; s < 2; s++) {
    int u = 4 * (2 * Wv + s) + lq;
    wh[s] = lr * 256 + ((2 * u) ^ ((lr & 7) << 4));
  }

  // coalesced h1 store mapping: wave Wv owns row Wv, lane sj -> u32 (2 units)
  int srow = Wv, sj = l;
  int sld = srow * 256 + ((4 * sj) ^ ((srow & 7) << 4));
  unsigned short* h1st = h1 + (long)(lrow + srow) * 8192 + 2 * sj;

  const bf16x8* xp = (const bf16x8*)xpk + (grow0 >> 4) * 4096 + l;
  bf16x8 xb = xp[0];
  __syncthreads();

  for (int t = 0; t < 64; t++) {
    const unsigned char* rbuf = hlds[t & 1];
    unsigned char* wbuf = hlds[(t & 1) ^ 1];
    bf16x8 xb_n = xb;
    if (t < 63) xb_n = xp[(t + 1) * 64];   // prefetch next step's x frag

    f32x4 acc[2];
    acc[0] = (f32x4){0.f, 0.f, 0.f, 0.f};
    acc[1] = (f32x4){0.f, 0.f, 0.f, 0.f};
#pragma unroll
    for (int kt = 0; kt < 4; kt++) {
      bf16x8 hb = *(const bf16x8*)(rbuf + rd[kt]);
      acc[0] = __builtin_amdgcn_mfma_f32_16x16x32_bf16(Af[0][kt], hb, acc[0], 0, 0, 0);
      acc[1] = __builtin_amdgcn_mfma_f32_16x16x32_bf16(Af[1][kt], hb, acc[1], 0, 0, 0);
    }
    acc[0] = __builtin_amdgcn_mfma_f32_16x16x32_bf16(Af[0][4], xb, acc[0], 0, 0, 0);
    acc[1] = __builtin_amdgcn_mfma_f32_16x16x32_bf16(Af[1][4], xb, acc[1], 0, 0, 0);
#pragma unroll
    for (int s = 0; s < 2; s++) {
      float h = cell2(acc[s], c_st[s]);
      *(unsigned short*)(wbuf + wh[s]) = f2bf(h);
    }
    xb = xb_n;
    __syncthreads();
    // h(t) now complete in wbuf: coalesced global store (256B/wave contiguous)
    *(unsigned int*)(h1st + t * 128) =
        *(const unsigned int*)(hlds[(t & 1) ^ 1] + sld);
  }
}

// ---------------- LSTM layer 1: 16 rows/block, 16 waves --------------------
__global__ __launch_bounds__(1024, 4) void lstm1_k(char* __restrict__ ws, int row_base)
{
  const unsigned short* W1pk = (const unsigned short*)(ws + O_W1PK);
  const float* bias1 = (const float*)(ws + O_BIAS1);
  const unsigned short* h1 = (const unsigned short*)(ws + O_H1);
  unsigned short* hTt = (unsigned short*)(ws + O_HTT);

  int tid = threadIdx.x;
  int W = tid >> 6, l = tid & 63, lr = l & 15, lq = l >> 4;
  int lrow = blockIdx.x * 16;
  long grow0 = (long)row_base + lrow;

  __shared__ unsigned char hlds[2][4096];  // h1-layer state
  __shared__ unsigned char h1s[2][4096];   // staged h1 input
  ((unsigned int*)hlds[0])[tid] = 0u;

  // h1 staging: each thread owns (prow = tid>>6, unit-pair c = tid&63)
  int prow = tid >> 6, pc = tid & 63;
  const unsigned short* h1src = h1 + ((long)(lrow + prow) * 64) * 128 + 2 * pc;
  int h1dst = prow * 256 + ((4 * pc) ^ ((prow & 7) << 4));
  *(unsigned int*)(h1s[0] + h1dst) = *(const unsigned int*)h1src;  // t=0

  bf16x8 Af[2][8];
#pragma unroll
  for (int s = 0; s < 2; s++)
#pragma unroll
    for (int kt = 0; kt < 8; kt++)
      Af[s][kt] = ((const bf16x8*)W1pk)[(((2 * W + s) * 8) + kt) * 64 + l];

  f32x4 bias_c[2];
#pragma unroll
  for (int s = 0; s < 2; s++)
#pragma unroll
    for (int r = 0; r < 4; r++)
      bias_c[s][r] = bias1[r * 128 + 4 * (2 * W + s) + lq];

  float c_st[2] = {0.f, 0.f};

  int rd[4], wh[2];
#pragma unroll
  for (int kt = 0; kt < 4; kt++)
    rd[kt] = lr * 256 + ((64 * kt + 16 * lq) ^ ((lr & 7) << 4));
#pragma unroll
  for (int s = 0; s < 2; s++) {
    int u = 4 * (2 * W + s) + lq;
    wh[s] = lr * 256 + ((2 * u) ^ ((lr & 7) << 4));
  }
  __syncthreads();

  for (int t = 0; t < 64; t++) {
    const unsigned char* rbuf = hlds[t & 1];
    unsigned char* wbuf = hlds[(t & 1) ^ 1];
    const unsigned char* h1r = h1s[t & 1];
    unsigned char* h1w = h1s[(t & 1) ^ 1];
    // prefetch next h1 tile (issue early, write late)
    int tn = (t + 1) & 63;
    unsigned int pf = *(const unsigned int*)(h1src + tn * 128);

    f32x4 acc[2];
    acc[0] = bias_c[0]; acc[1] = bias_c[1];
#pragma unroll
    for (int kt = 0; kt < 4; kt++) {
      bf16x8 xb = *(const bf16x8*)(h1r + rd[kt]);
      acc[0] = __builtin_amdgcn_mfma_f32_16x16x32_bf16(Af[0][kt], xb, acc[0], 0, 0, 0);
      acc[1] = __builtin_amdgcn_mfma_f32_16x16x32_bf16(Af[1][kt], xb, acc[1], 0, 0, 0);
    }
#pragma unroll
    for (int kt = 0; kt < 4; kt++) {
      bf16x8 hb = *(const bf16x8*)(rbuf + rd[kt]);
      acc[0] = __builtin_amdgcn_mfma_f32_16x16x32_bf16(Af[0][4 + kt], hb, acc[0], 0, 0, 0);
      acc[1] = __builtin_amdgcn_mfma_f32_16x16x32_bf16(Af[1][4 + kt], hb, acc[1], 0, 0, 0);
    }
#pragma unroll
    for (int s = 0; s < 2; s++) {
      float h = cell2(acc[s], c_st[s]);
      unsigned short hb16 = f2bf(h);
      *(unsigned short*)(wbuf + wh[s]) = hb16;
      if (t == 63) {
        long grow = grow0 + lr;
        int u = 4 * (2 * W + s) + lq;
        hTt[((grow >> 8) * 128 + u) * 256 + (grow & 255)] = hb16;
      }
    }
    *(unsigned int*)(h1w + h1dst) = pf;
    __syncthreads();
  }
}

// ---------------- graph stage (unchanged, verified) ------------------------
__global__ __launch_bounds__(256, 2) void g1_kernel(char* __restrict__ ws)
{
  const unsigned short* hTt = (const unsigned short*)(ws + O_HTT);
  const unsigned short* Apk = (const unsigned short*)(ws + O_APK);
  unsigned short* HAt = (unsigned short*)(ws + O_HAT);
  int tid = threadIdx.x, w = tid >> 6, l = tid & 63, lr = l & 15, lq = l >> 4;
  int bi = blockIdx.x;
  int b = bi >> 3, rtp = (bi >> 1) & 3, ch = bi & 1;
  f32x4 acc[2][2];
#pragma unroll
  for (int i = 0; i < 2; i++)
#pragma unroll
    for (int j = 0; j < 2; j++) acc[i][j] = (f32x4){0.f, 0.f, 0.f, 0.f};
  for (int kt = 0; kt < 8; kt++) {
    bf16x8 af[2];
#pragma unroll
    for (int rtl = 0; rtl < 2; rtl++) {
      int rt = rtp * 2 + rtl;
      af[rtl] = *(const bf16x8*)(hTt + (long)(b * 128 + 16 * rt + lr) * 256 + 32 * kt + 8 * lq);
    }
#pragma unroll
    for (int cti = 0; cti < 2; cti++) {
      int ct = w * 4 + ch * 2 + cti;
      bf16x8 bf = ((const bf16x8*)Apk)[(ct * 8 + kt) * 64 + l];
#pragma unroll
      for (int rtl = 0; rtl < 2; rtl++)
        acc[rtl][cti] = __builtin_amdgcn_mfma_f32_16x16x32_bf16(af[rtl], bf, acc[rtl][cti], 0, 0, 0);
    }
  }
#pragma unroll
  for (int rtl = 0; rtl < 2; rtl++)
#pragma unroll
    for (int cti = 0; cti < 2; cti++) {
      int rt = rtp * 2 + rtl, ct = w * 4 + ch * 2 + cti;
      u16x4 pk;
#pragma unroll
      for (int r = 0; r < 4; r++) pk[r] = f2bf(acc[rtl][cti][r]);
      *(u16x4*)(HAt + (long)(b * 256 + 16 * ct + lr) * 128 + 16 * rt + 4 * lq) = pk;
    }
}

__global__ __launch_bounds__(256, 2) void g2_kernel(char* __restrict__ ws)
{
  const unsigned short* HAt = (const unsigned short*)(ws + O_HAT);
  const unsigned short* W1apk = (const unsigned short*)(ws + O_W1APK);
  const unsigned short* W2apk = (const unsigned short*)(ws + O_W2APK);
  unsigned short* W1hAt = (unsigned short*)(ws + O_W1HAT);
  unsigned short* midT = (unsigned short*)(ws + O_MIDT);
  int tid = threadIdx.x, w = tid >> 6, l = tid & 63, lr = l & 15, lq = l >> 4;
  int bi = blockIdx.x;
  int b = bi >> 3, rtp = (bi >> 1) & 3, ch = bi & 1;
  f32x4 a1[2][2], a2[2][2];
#pragma unroll
  for (int i = 0; i < 2; i++)
#pragma unroll
    for (int j = 0; j < 2; j++) { a1[i][j] = (f32x4){0.f,0.f,0.f,0.f}; a2[i][j] = (f32x4){0.f,0.f,0.f,0.f}; }
  for (int kt = 0; kt < 4; kt++) {
    bf16x8 af1[2], af2[2];
#pragma unroll
    for (int rtl = 0; rtl < 2; rtl++) {
      int rt = rtp * 2 + rtl;
      af1[rtl] = ((const bf16x8*)W1apk)[(rt * 4 + kt) * 64 + l];
      af2[rtl] = ((const bf16x8*)W2apk)[(rt * 4 + kt) * 64 + l];
    }
#pragma unroll
    for (int cti = 0; cti < 2; cti++) {
      int ct = w * 4 + ch * 2 + cti;
      bf16x8 bf = *(const bf16x8*)(HAt + (long)(b * 256 + 16 * ct + lr) * 128 + 32 * kt + 8 * lq);
#pragma unroll
      for (int rtl = 0; rtl < 2; rtl++) {
        a1[rtl][cti] = __builtin_amdgcn_mfma_f32_16x16x32_bf16(af1[rtl], bf, a1[rtl][cti], 0, 0, 0);
        a2[rtl][cti] = __builtin_amdgcn_mfma_f32_16x16x32_bf16(af2[rtl], bf, a2[rtl][cti], 0, 0, 0);
      }
    }
  }
#pragma unroll
  for (int rtl = 0; rtl < 2; rtl++)
#pragma unroll
    for (int cti = 0; cti < 2; cti++) {
      int rt = rtp * 2 + rtl, ct = w * 4 + ch * 2 + cti;
      u16x4 p1, p2;
#pragma unroll
      for (int r = 0; r < 4; r++) {
        p1[r] = f2bf(a1[rtl][cti][r]);
        p2[r] = f2bf(fmaxf(a2[rtl][cti][r], 0.f));
      }
      long off = (long)(b * 256 + 16 * ct + lr) * 128 + 16 * rt + 4 * lq;
      *(u16x4*)(W1hAt + off) = p1;
      *(u16x4*)(midT + off) = p2;
    }
}

__global__ __launch_bounds__(256, 2) void g3_kernel(char* __restrict__ ws)
{
  const unsigned short* midT = (const unsigned short*)(ws + O_MIDT);
  const unsigned short* W3apk = (const unsigned short*)(ws + O_W3APK);
  unsigned short* W3r = (unsigned short*)(ws + O_W3R);
  int tid = threadIdx.x, w = tid >> 6, l = tid & 63, lr = l & 15, lq = l >> 4;
  int bi = blockIdx.x;
  int b = bi >> 3, rtp = (bi >> 1) & 3, ch = bi & 1;
  f32x4 acc[2][2];
#pragma unroll
  for (int i = 0; i < 2; i++)
#pragma unroll
    for (int j = 0; j < 2; j++) acc[i][j] = (f32x4){0.f, 0.f, 0.f, 0.f};
  for (int kt = 0; kt < 4; kt++) {
    bf16x8 af[2];
#pragma unroll
    for (int rtl = 0; rtl < 2; rtl++)
      af[rtl] = ((const bf16x8*)W3apk)[((rtp * 2 + rtl) * 4 + kt) * 64 + l];
#pragma unroll
    for (int cti = 0; cti < 2; cti++) {
      int ct = w * 4 + ch * 2 + cti;
      bf16x8 bf = *(const bf16x8*)(midT + (long)(b * 256 + 16 * ct + lr) * 128 + 32 * kt + 8 * lq);
#pragma unroll
      for (int rtl = 0; rtl < 2; rtl++)
        acc[rtl][cti] = __builtin_amdgcn_mfma_f32_16x16x32_bf16(af[rtl], bf, acc[rtl][cti], 0, 0, 0);
    }
  }
#pragma unroll
  for (int rtl = 0; rtl < 2; rtl++)
#pragma unroll
    for (int cti = 0; cti < 2; cti++) {
      int rt = rtp * 2 + rtl, ct = w * 4 + ch * 2 + cti;
#pragma unroll
      for (int r = 0; r < 4; r++)
        W3r[(long)(b * 128 + 16 * rt + 4 * lq + r) * 256 + 16 * ct + lr] = f2bf(acc[rtl][cti][r]);
    }
}

__global__ __launch_bounds__(256, 2) void g4_kernel(char* __restrict__ ws,
    const float* __restrict__ Wfc, float* __restrict__ out)
{
  const unsigned short* W3r = (const unsigned short*)(ws + O_W3R);
  const unsigned short* Apk = (const unsigned short*)(ws + O_APK);
  const unsigned short* W1hAt = (const unsigned short*)(ws + O_W1HAT);
  int tid = threadIdx.x, w = tid >> 6, l = tid & 63, lr = l & 15, lq = l >> 4;
  int bi = blockIdx.x;
  int b = bi >> 2, cq = bi & 3;
  int ct = cq * 4 + w;
  f32x4 acc[8];
#pragma unroll
  for (int i = 0; i < 8; i++) acc[i] = (f32x4){0.f, 0.f, 0.f, 0.f};
  for (int kt = 0; kt < 8; kt++) {
    bf16x8 bfv = ((const bf16x8*)Apk)[(ct * 8 + kt) * 64 + l];
#pragma unroll
    for (int rt = 0; rt < 8; rt++) {
      bf16x8 af = *(const bf16x8*)(W3r + (long)(b * 128 + 16 * rt + lr) * 256 + 32 * kt + 8 * lq);
      acc[rt] = __builtin_amdgcn_mfma_f32_16x16x32_bf16(af, bfv, acc[rt], 0, 0, 0);
    }
  }
  float psum = 0.f;
#pragma unroll
  for (int rt = 0; rt < 8; rt++) {
    float4 wf = *(const float4*)(Wfc + 16 * rt + 4 * lq);
    u16x4 wv = *(const u16x4*)(W1hAt + (long)(b * 256 + 16 * ct + lr) * 128 + 16 * rt + 4 * lq);
    psum += wf.x * (0.1f * acc[rt][0] + 0.9f * bf2f(wv[0]));
    psum += wf.y * (0.1f * acc[rt][1] + 0.9f * bf2f(wv[1]));
    psum += wf.z * (0.1f * acc[rt][2] + 0.9f * bf2f(wv[2]));
    psum += wf.w * (0.1f * acc[rt][3] + 0.9f * bf2f(wv[3]));
  }
  psum += __shfl_xor(psum, 16);
  psum += __shfl_xor(psum, 32);
  if (lq == 0) out[b * 256 + ct * 16 + lr] = __builtin_amdgcn_rcpf(1.f + exp2f(-1.44269504f * psum));
}

// ---------------------------------------------------------------------------
extern "C" void kernel_launch(void* const* d_in, const int* in_sizes, int n_in,
                              void* d_out, int out_size, void* d_ws, size_t ws_size,
                              hipStream_t stream)
{
  const float* x    = (const float*)d_in[0];
  const float* A    = (const float*)d_in[1];
  const float* Wih0 = (const float*)d_in[2];
  const float* Whh0 = (const float*)d_in[3];
  const float* bih0 = (const float*)d_in[4];
  const float* bhh0 = (const float*)d_in[5];
  const float* Wih1 = (const float*)d_in[6];
  const float* Whh1 = (const float*)d_in[7];
  const float* bih1 = (const float*)d_in[8];
  const float* bhh1 = (const float*)d_in[9];
  const float* W1   = (const float*)d_in[10];
  const float* W2   = (const float*)d_in[11];
  const float* W3   = (const float*)d_in[12];
  const float* Wfc  = (const float*)d_in[13];
  char* ws = (char*)d_ws;

  prep_kernel<<<(PREP_TOT + 255) / 256, 256, 0, stream>>>(
      A, Wih0, Whh0, bih0, bhh0, Wih1, Whh1, bih1, bhh1, W1, W2, W3, ws);
  prepx_kernel<<<8192, 256, 0, stream>>>(x, ws);

  size_t need_full = (size_t)O_H1 + 134217728u;  // 8192-row h1
  size_t need_half = (size_t)O_H1 + 67108864u;   // 4096-row h1
  if (ws_size >= need_full) {
    lstm0_k<<<512, 1024, 0, stream>>>(ws, 0);
    lstm1_k<<<512, 1024, 0, stream>>>(ws, 0);
  } else if (ws_size >= need_half) {
    for (int c = 0; c < 2; c++) {
      lstm0_k<<<256, 1024, 0, stream>>>(ws, c * 4096);
      lstm1_k<<<256, 1024, 0, stream>>>(ws, c * 4096);
    }
  } else {
    for (int c = 0; c < 4; c++) {
      lstm0_k<<<128, 1024, 0, stream>>>(ws, c * 2048);
      lstm1_k<<<128, 1024, 0, stream>>>(ws, c * 2048);
    }
  }

  g1_kernel<<<256, 256, 0, stream>>>(ws);
  g2_kernel<<<256, 256, 0, stream>>>(ws);
  g3_kernel<<<256, 256, 0, stream>>>(ws);
  g4_kernel<<<128, 256, 0, stream>>>(ws, Wfc, (float*)d_out);
}

// Round 5
// 333.626 us; speedup vs baseline: 2.0116x; 1.0721x over previous
//
#include <hip/hip_runtime.h>

// ---------------------------------------------------------------------------
// 2-layer LSTM (BN=8192 seqs, T=64, F=16, H=128) + graph mixing stage.
// LSTM gates: G^T = W_packed . h^T (A=weights in VGPR/AGPR, B=h from LDS).
// Unit mapping (round 5): wave W, acc s, lane-quad lq -> unit u = 8W + 2lq + s
//   gate-row gr = 16*(2W+s) + 4*lq + p  (p = gate i/f/g/o = acc reg index)
//   => lane's two cells (s=0,1) are ADJACENT units -> single u32 LDS write
//      via v_cvt_pk_bf16_f32.
// MFMA frag conventions (verified rounds 1-4):
//   A-frag: lane l holds A[16*rt + (l&15)][32*kt + 8*(l>>4) + i], i=0..7
//   B-frag: lane l holds B[32*kt + 8*(l>>4) + i][16*ct + (l&15)]
//   D:      lane l, reg r holds D[16*rt + 4*(l>>4) + r][16*ct + (l&15)]
// ---------------------------------------------------------------------------

typedef __attribute__((ext_vector_type(4))) float f32x4;
typedef __attribute__((ext_vector_type(2))) float f32x2;
typedef __attribute__((ext_vector_type(8))) __bf16 bf16x8;
typedef __attribute__((ext_vector_type(8))) unsigned short u16x8;
typedef __attribute__((ext_vector_type(4))) unsigned short u16x4;

#define DEV static __device__ __forceinline__

DEV unsigned short f2bf(float f) {
  unsigned u = __builtin_bit_cast(unsigned, f);
  u = u + 0x7fffu + ((u >> 16) & 1u);
  return (unsigned short)(u >> 16);
}
DEV float bf2f(unsigned short s) {
  unsigned u = ((unsigned)s) << 16;
  return __builtin_bit_cast(float, u);
}

DEV f32x2 exp2v2(f32x2 x) { f32x2 r; r[0] = exp2f(x[0]); r[1] = exp2f(x[1]); return r; }
DEV f32x2 rcpv2(f32x2 x) {
  f32x2 r; r[0] = __builtin_amdgcn_rcpf(x[0]); r[1] = __builtin_amdgcn_rcpf(x[1]); return r;
}

// Two independent LSTM cells in packed f32x2 lanes; gates per cell i,f,g,o.
// Returns packed bf16 pair (lo = cell s=0, hi = cell s=1).
DEV unsigned cell_pair(f32x2 gi, f32x2 gf, f32x2 gg, f32x2 go, f32x2& c) {
  const float K1 = 1.44269504f, K2 = 2.88539008f;
  f32x2 t1 = exp2v2((f32x2){K2 * gg[0], K2 * gg[1]});
  f32x2 t2 = exp2v2((f32x2){-K1 * gi[0], -K1 * gi[1]});
  f32x2 ef = exp2v2((f32x2){-K1 * gf[0], -K1 * gf[1]});
  f32x2 one = {1.f, 1.f};
  f32x2 d1 = t1 + one;
  f32x2 den1 = d1 * t2 + d1;
  f32x2 it = (t1 - one) * rcpv2(den1);          // sig(i)*tanh(g)
  c = rcpv2(one + ef) * c + it;                 // sig(f)*c + it
  f32x2 t3 = exp2v2((f32x2){K2 * c[0], K2 * c[1]});
  f32x2 t4 = exp2v2((f32x2){-K1 * go[0], -K1 * go[1]});
  f32x2 d3 = t3 + one;
  f32x2 den3 = d3 * t4 + d3;
  f32x2 h = (t3 - one) * rcpv2(den3);           // sig(o)*tanh(c)
  unsigned r;
  asm("v_cvt_pk_bf16_f32 %0, %1, %2" : "=v"(r) : "v"(h[0]), "v"(h[1]));
  return r;
}

// ---------------- workspace layout (bytes) ----------------
#define O_W0PK   0            // 32rt*5kt*64l*8i bf16 = 163840
#define O_W1PK   163840       // 32rt*8kt*64l*8i bf16 = 262144
#define O_APK    425984       // 131072
#define O_W1APK  557056       // 32768
#define O_W2APK  589824       // 32768
#define O_W3APK  622592       // 32768
#define O_BIAS0  655360       // 2048
#define O_BIAS1  657408       // 2048
#define O_HTT    659456       // 2097152  hT^T [32][128][256] bf16
#define O_HAT    2756608      // 2097152
#define O_MIDT   4853760      // 2097152
#define O_W1HAT  6950912      // 2097152
#define O_W3R    9048064      // 2097152
#define O_XPK    11145216     // 33554432 x B-frags (padded K=32, pad col16=1.0)
#define O_H1     44699648     // up to 128 MiB h1 [row][t][128] bf16

#define PREP_TOT 328704

// unit for packed gate-row tile rt, lane-quad lq, within-pair s = rt&1
DEV int gr_unit(int rt, int lq2, int s) { return 8 * (rt >> 1) + 2 * lq2 + s; }

// ---------------- prepass: pack weights -----------------------------------
__global__ void prep_kernel(const float* __restrict__ A,
    const float* __restrict__ Wih0, const float* __restrict__ Whh0,
    const float* __restrict__ bih0, const float* __restrict__ bhh0,
    const float* __restrict__ Wih1, const float* __restrict__ Whh1,
    const float* __restrict__ bih1, const float* __restrict__ bhh1,
    const float* __restrict__ W1, const float* __restrict__ W2,
    const float* __restrict__ W3, char* __restrict__ ws)
{
  int idx = blockIdx.x * blockDim.x + threadIdx.x;
  if (idx >= PREP_TOT) return;
  if (idx < 81920) {                       // W0pk A-frags
    int o = idx, i = o & 7, l = (o >> 3) & 63, f = o >> 9;
    int kt = f % 5, rt = f / 5;
    int lr = l & 15, lq = l >> 4;
    int p = lr & 3, lql = (lr >> 2) & 3;
    int gc = p * 128 + gr_unit(rt, lql, rt & 1);
    float v;
    if (kt < 4) v = Whh0[gc * 128 + 32 * kt + 8 * lq + i];
    else {
      int kk = 8 * lq + i;
      v = (kk < 16) ? Wih0[gc * 16 + kk]
                    : (kk == 16 ? (bih0[gc] + bhh0[gc]) : 0.f);  // bias row
    }
    ((unsigned short*)(ws + O_W0PK))[idx] = f2bf(v);
  } else if (idx < 212992) {               // W1pk: kt<4 = h1-input, kt>=4 = recurrent
    int o = idx - 81920, i = o & 7, l = (o >> 3) & 63, f = o >> 9;
    int kt = f & 7, rt = f >> 3;
    int lr = l & 15, lq = l >> 4;
    int p = lr & 3, lql = (lr >> 2) & 3;
    int gc = p * 128 + gr_unit(rt, lql, rt & 1);
    float v = (kt < 4) ? Wih1[gc * 128 + 32 * kt + 8 * lq + i]
                       : Whh1[gc * 128 + 32 * (kt - 4) + 8 * lq + i];
    ((unsigned short*)(ws + O_W1PK))[o] = f2bf(v);
  } else if (idx < 278528) {               // Apk = sigmoid(A) B-frags
    int o = idx - 212992, i = o & 7, l = (o >> 3) & 63, f = o >> 9;
    int kt = f & 7, ct = f >> 3;
    int n = 32 * kt + 8 * (l >> 4) + i;
    int lc = 16 * ct + (l & 15);
    float e = exp2f(-1.44269504f * A[n * 256 + lc]);
    ((unsigned short*)(ws + O_APK))[o] = f2bf(__builtin_amdgcn_rcpf(1.f + e));
  } else if (idx < 327680) {               // W1/W2/W3 A-frags (graph stage)
    int o = idx - 278528;
    int m = o >> 14;
    int oo = o & 16383;
    int i = oo & 7, l = (oo >> 3) & 63, f = oo >> 9;
    int kt = f & 3, rt = f >> 2;
    int g = 16 * rt + (l & 15);
    int k = 32 * kt + 8 * (l >> 4) + i;
    const float* W = (m == 0) ? W1 : (m == 1) ? W2 : W3;
    unsigned short* dst = (unsigned short*)(ws + ((m == 0) ? O_W1APK : (m == 1) ? O_W2APK : O_W3APK));
    dst[oo] = f2bf(W[g * 128 + k]);
  } else if (idx < 328192) {
    int c = idx - 327680;
    ((float*)(ws + O_BIAS0))[c] = bih0[c] + bhh0[c];
  } else {
    int c = idx - 328192;
    ((float*)(ws + O_BIAS1))[c] = bih1[c] + bhh1[c];
  }
}

// x -> padded B-frag bf16; pad column k=16 = 1.0 (bias multiplier)
__global__ void prepx_kernel(const float* __restrict__ x, char* __restrict__ ws)
{
  int tid = blockIdx.x * 256 + threadIdx.x;     // 0 .. 2097151
  int dat = (tid < 1048576) ? 1 : 0;
  int id = tid & 1048575;
  int half = id & 1, t = (id >> 1) & 63, row = id >> 7;
  u16x8 v = (u16x8)0;
  if (dat) {
    const float* p = x + ((long)row * 64 + t) * 16 + 8 * half;
    float4 a = *(const float4*)p;
    float4 b = *(const float4*)(p + 4);
    v[0] = f2bf(a.x); v[1] = f2bf(a.y); v[2] = f2bf(a.z); v[3] = f2bf(a.w);
    v[4] = f2bf(b.x); v[5] = f2bf(b.y); v[6] = f2bf(b.z); v[7] = f2bf(b.w);
  } else if (half == 0) {
    v[0] = 0x3F80;                              // k=16 -> 1.0f (bias column)
  }
  int lane = (dat ? 0 : 32) + half * 16 + (row & 15);
  int rt = row >> 4;
  ((u16x8*)(ws + O_XPK))[(rt * 64 + t) * 64 + lane] = v;
}

// ---------------- LSTM layer 0: 32 rows/block, 16 waves, 1 barrier/step ----
__global__ __launch_bounds__(1024, 4) void lstm0_k(char* __restrict__ ws, int row_base)
{
  const unsigned short* W0pk = (const unsigned short*)(ws + O_W0PK);
  const unsigned short* xpk = (const unsigned short*)(ws + O_XPK);
  unsigned short* h1 = (unsigned short*)(ws + O_H1);

  int tid = threadIdx.x;
  int Wv = tid >> 6, l = tid & 63, lr = l & 15, lq = l >> 4;
  int lrow = blockIdx.x * 32;
  long grow0 = (long)row_base + lrow;

  __shared__ unsigned char hlds[2][8192];  // h state [32 rows][128 u] swizzled
  ((u16x8*)hlds[0])[tid] = (u16x8)0;       // zero both buffers (16 KB)

  bf16x8 Af[2][5];                          // A-tiles rt = 2Wv+s
#pragma unroll
  for (int s = 0; s < 2; s++)
#pragma unroll
    for (int kt = 0; kt < 5; kt++)
      Af[s][kt] = ((const bf16x8*)W0pk)[(((2 * Wv + s) * 5) + kt) * 64 + l];

  f32x2 c_st[2] = {{0.f, 0.f}, {0.f, 0.f}};  // [ct], lanes = s

  int rd[2][4], whp[2];
#pragma unroll
  for (int ct = 0; ct < 2; ct++) {
#pragma unroll
    for (int kt = 0; kt < 4; kt++)
      rd[ct][kt] = (16 * ct + lr) * 256 + ((64 * kt + 16 * lq) ^ ((lr & 7) << 4));
    whp[ct] = (16 * ct + lr) * 256 + ((16 * Wv + 4 * lq) ^ ((lr & 7) << 4));
  }

  // coalesced h1 bounce: thread -> rows pr, pr+16, u32 col sj
  int pr = tid >> 6, sj = tid & 63;
  int sld0 = pr * 256 + ((4 * sj) ^ ((pr & 7) << 4));
  int sld1 = (pr + 16) * 256 + ((4 * sj) ^ ((pr & 7) << 4));
  unsigned short* st0 = h1 + (long)(lrow + pr) * 8192 + 2 * sj;
  unsigned short* st1 = h1 + (long)(lrow + pr + 16) * 8192 + 2 * sj;

  const bf16x8* xp0 = (const bf16x8*)xpk + ((grow0 >> 4) + 0) * 4096 + l;
  const bf16x8* xp1 = (const bf16x8*)xpk + ((grow0 >> 4) + 1) * 4096 + l;
  bf16x8 xb[2] = {xp0[0], xp1[0]};
  __syncthreads();

  for (int t = 0; t < 64; t++) {
    const unsigned char* rbuf = hlds[t & 1];
    unsigned char* wbuf = hlds[(t & 1) ^ 1];
    bf16x8 xbn[2] = {xb[0], xb[1]};
    if (t < 63) { xbn[0] = xp0[(t + 1) * 64]; xbn[1] = xp1[(t + 1) * 64]; }

    f32x4 acc[2][2];
#pragma unroll
    for (int ct = 0; ct < 2; ct++)
#pragma unroll
      for (int s = 0; s < 2; s++) acc[ct][s] = (f32x4){0.f, 0.f, 0.f, 0.f};
#pragma unroll
    for (int kt = 0; kt < 4; kt++) {
      bf16x8 hb0 = *(const bf16x8*)(rbuf + rd[0][kt]);
      bf16x8 hb1 = *(const bf16x8*)(rbuf + rd[1][kt]);
      acc[0][0] = __builtin_amdgcn_mfma_f32_16x16x32_bf16(Af[0][kt], hb0, acc[0][0], 0, 0, 0);
      acc[0][1] = __builtin_amdgcn_mfma_f32_16x16x32_bf16(Af[1][kt], hb0, acc[0][1], 0, 0, 0);
      acc[1][0] = __builtin_amdgcn_mfma_f32_16x16x32_bf16(Af[0][kt], hb1, acc[1][0], 0, 0, 0);
      acc[1][1] = __builtin_amdgcn_mfma_f32_16x16x32_bf16(Af[1][kt], hb1, acc[1][1], 0, 0, 0);
    }
    acc[0][0] = __builtin_amdgcn_mfma_f32_16x16x32_bf16(Af[0][4], xb[0], acc[0][0], 0, 0, 0);
    acc[0][1] = __builtin_amdgcn_mfma_f32_16x16x32_bf16(Af[1][4], xb[0], acc[0][1], 0, 0, 0);
    acc[1][0] = __builtin_amdgcn_mfma_f32_16x16x32_bf16(Af[0][4], xb[1], acc[1][0], 0, 0, 0);
    acc[1][1] = __builtin_amdgcn_mfma_f32_16x16x32_bf16(Af[1][4], xb[1], acc[1][1], 0, 0, 0);
#pragma unroll
    for (int ct = 0; ct < 2; ct++) {
      f32x2 gi = {acc[ct][0][0], acc[ct][1][0]};
      f32x2 gf = {acc[ct][0][1], acc[ct][1][1]};
      f32x2 gg = {acc[ct][0][2], acc[ct][1][2]};
      f32x2 go = {acc[ct][0][3], acc[ct][1][3]};
      *(unsigned*)(wbuf + whp[ct]) = cell_pair(gi, gf, gg, go, c_st[ct]);
    }
    xb[0] = xbn[0]; xb[1] = xbn[1];
    __syncthreads();
    // h(t) complete in wbuf: coalesced global store (256B contiguous per wave)
    *(unsigned*)(st0 + t * 128) = *(const unsigned*)(hlds[(t & 1) ^ 1] + sld0);
    *(unsigned*)(st1 + t * 128) = *(const unsigned*)(hlds[(t & 1) ^ 1] + sld1);
  }
}

// ---------------- LSTM layer 1: 32 rows/block, 16 waves --------------------
__global__ __launch_bounds__(1024, 4) void lstm1_k(char* __restrict__ ws, int row_base)
{
  const unsigned short* W1pk = (const unsigned short*)(ws + O_W1PK);
  const float* bias1 = (const float*)(ws + O_BIAS1);
  const unsigned short* h1 = (const unsigned short*)(ws + O_H1);
  unsigned short* hTt = (unsigned short*)(ws + O_HTT);

  int tid = threadIdx.x;
  int Wv = tid >> 6, l = tid & 63, lr = l & 15, lq = l >> 4;
  int lrow = blockIdx.x * 32;
  long grow0 = (long)row_base + lrow;

  __shared__ unsigned char hlds[2][8192];  // layer-1 h state
  __shared__ unsigned char h1s[2][8192];   // staged h1 input
  ((u16x8*)hlds[0])[tid] = (u16x8)0;

  // h1 staging: thread -> rows prow, prow+16, u32 col pc
  int prow = tid >> 6, pc = tid & 63;
  const unsigned short* s0 = h1 + (long)(lrow + prow) * 8192 + 2 * pc;
  const unsigned short* s1 = h1 + (long)(lrow + prow + 16) * 8192 + 2 * pc;
  int d0 = prow * 256 + ((4 * pc) ^ ((prow & 7) << 4));
  int d1 = (prow + 16) * 256 + ((4 * pc) ^ ((prow & 7) << 4));
  *(unsigned*)(h1s[0] + d0) = *(const unsigned*)s0;   // t = 0
  *(unsigned*)(h1s[0] + d1) = *(const unsigned*)s1;

  bf16x8 Af[2][8];
#pragma unroll
  for (int s = 0; s < 2; s++)
#pragma unroll
    for (int kt = 0; kt < 8; kt++)
      Af[s][kt] = ((const bf16x8*)W1pk)[(((2 * Wv + s) * 8) + kt) * 64 + l];

  f32x4 bias_c[2];
#pragma unroll
  for (int s = 0; s < 2; s++)
#pragma unroll
    for (int r = 0; r < 4; r++)
      bias_c[s][r] = bias1[r * 128 + 8 * Wv + 2 * lq + s];

  f32x2 c_st[2] = {{0.f, 0.f}, {0.f, 0.f}};

  int rd[2][4], whp[2];
#pragma unroll
  for (int ct = 0; ct < 2; ct++) {
#pragma unroll
    for (int kt = 0; kt < 4; kt++)
      rd[ct][kt] = (16 * ct + lr) * 256 + ((64 * kt + 16 * lq) ^ ((lr & 7) << 4));
    whp[ct] = (16 * ct + lr) * 256 + ((16 * Wv + 4 * lq) ^ ((lr & 7) << 4));
  }
  __syncthreads();

  for (int t = 0; t < 64; t++) {
    const unsigned char* rbuf = hlds[t & 1];
    unsigned char* wbuf = hlds[(t & 1) ^ 1];
    const unsigned char* h1r = h1s[t & 1];
    unsigned char* h1w = h1s[(t & 1) ^ 1];
    int tn = (t < 63) ? t + 1 : 63;
    unsigned pf0 = *(const unsigned*)(s0 + tn * 128);
    unsigned pf1 = *(const unsigned*)(s1 + tn * 128);

    f32x4 acc[2][2];
#pragma unroll
    for (int ct = 0; ct < 2; ct++) {
      acc[ct][0] = bias_c[0]; acc[ct][1] = bias_c[1];
    }
#pragma unroll
    for (int kt = 0; kt < 4; kt++) {
      bf16x8 xb0 = *(const bf16x8*)(h1r + rd[0][kt]);
      bf16x8 xb1 = *(const bf16x8*)(h1r + rd[1][kt]);
      acc[0][0] = __builtin_amdgcn_mfma_f32_16x16x32_bf16(Af[0][kt], xb0, acc[0][0], 0, 0, 0);
      acc[0][1] = __builtin_amdgcn_mfma_f32_16x16x32_bf16(Af[1][kt], xb0, acc[0][1], 0, 0, 0);
      acc[1][0] = __builtin_amdgcn_mfma_f32_16x16x32_bf16(Af[0][kt], xb1, acc[1][0], 0, 0, 0);
      acc[1][1] = __builtin_amdgcn_mfma_f32_16x16x32_bf16(Af[1][kt], xb1, acc[1][1], 0, 0, 0);
    }
#pragma unroll
    for (int kt = 0; kt < 4; kt++) {
      bf16x8 hb0 = *(const bf16x8*)(rbuf + rd[0][kt]);
      bf16x8 hb1 = *(const bf16x8*)(rbuf + rd[1][kt]);
      acc[0][0] = __builtin_amdgcn_mfma_f32_16x16x32_bf16(Af[0][4 + kt], hb0, acc[0][0], 0, 0, 0);
      acc[0][1] = __builtin_amdgcn_mfma_f32_16x16x32_bf16(Af[1][4 + kt], hb0, acc[0][1], 0, 0, 0);
      acc[1][0] = __builtin_amdgcn_mfma_f32_16x16x32_bf16(Af[0][4 + kt], hb1, acc[1][0], 0, 0, 0);
      acc[1][1] = __builtin_amdgcn_mfma_f32_16x16x32_bf16(Af[1][4 + kt], hb1, acc[1][1], 0, 0, 0);
    }
#pragma unroll
    for (int ct = 0; ct < 2; ct++) {
      f32x2 gi = {acc[ct][0][0], acc[ct][1][0]};
      f32x2 gf = {acc[ct][0][1], acc[ct][1][1]};
      f32x2 gg = {acc[ct][0][2], acc[ct][1][2]};
      f32x2 go = {acc[ct][0][3], acc[ct][1][3]};
      unsigned hp = cell_pair(gi, gf, gg, go, c_st[ct]);
      *(unsigned*)(wbuf + whp[ct]) = hp;
      if (t == 63) {
        long grow = grow0 + 16 * ct + lr;
        long base = ((grow >> 8) * 128) * 256 + (grow & 255);
        int u0 = 8 * Wv + 2 * lq;
        hTt[base + (long)u0 * 256] = (unsigned short)(hp & 0xffff);
        hTt[base + (long)(u0 + 1) * 256] = (unsigned short)(hp >> 16);
      }
    }
    *(unsigned*)(h1w + d0) = pf0;
    *(unsigned*)(h1w + d1) = pf1;
    __syncthreads();
  }
}

// ---------------- graph stage (unchanged, verified) ------------------------
__global__ __launch_bounds__(256, 2) void g1_kernel(char* __restrict__ ws)
{
  const unsigned short* hTt = (const unsigned short*)(ws + O_HTT);
  const unsigned short* Apk = (const unsigned short*)(ws + O_APK);
  unsigned short* HAt = (unsigned short*)(ws + O_HAT);
  int tid = threadIdx.x, w = tid >> 6, l = tid & 63, lr = l & 15, lq = l >> 4;
  int bi = blockIdx.x;
  int b = bi >> 3, rtp = (bi >> 1) & 3, ch = bi & 1;
  f32x4 acc[2][2];
#pragma unroll
  for (int i = 0; i < 2; i++)
#pragma unroll
    for (int j = 0; j < 2; j++) acc[i][j] = (f32x4){0.f, 0.f, 0.f, 0.f};
  for (int kt = 0; kt < 8; kt++) {
    bf16x8 af[2];
#pragma unroll
    for (int rtl = 0; rtl < 2; rtl++) {
      int rt = rtp * 2 + rtl;
      af[rtl] = *(const bf16x8*)(hTt + (long)(b * 128 + 16 * rt + lr) * 256 + 32 * kt + 8 * lq);
    }
#pragma unroll
    for (int cti = 0; cti < 2; cti++) {
      int ct = w * 4 + ch * 2 + cti;
      bf16x8 bf = ((const bf16x8*)Apk)[(ct * 8 + kt) * 64 + l];
#pragma unroll
      for (int rtl = 0; rtl < 2; rtl++)
        acc[rtl][cti] = __builtin_amdgcn_mfma_f32_16x16x32_bf16(af[rtl], bf, acc[rtl][cti], 0, 0, 0);
    }
  }
#pragma unroll
  for (int rtl = 0; rtl < 2; rtl++)
#pragma unroll
    for (int cti = 0; cti < 2; cti++) {
      int rt = rtp * 2 + rtl, ct = w * 4 + ch * 2 + cti;
      u16x4 pk;
#pragma unroll
      for (int r = 0; r < 4; r++) pk[r] = f2bf(acc[rtl][cti][r]);
      *(u16x4*)(HAt + (long)(b * 256 + 16 * ct + lr) * 128 + 16 * rt + 4 * lq) = pk;
    }
}

__global__ __launch_bounds__(256, 2) void g2_kernel(char* __restrict__ ws)
{
  const unsigned short* HAt = (const unsigned short*)(ws + O_HAT);
  const unsigned short* W1apk = (const unsigned short*)(ws + O_W1APK);
  const unsigned short* W2apk = (const unsigned short*)(ws + O_W2APK);
  unsigned short* W1hAt = (unsigned short*)(ws + O_W1HAT);
  unsigned short* midT = (unsigned short*)(ws + O_MIDT);
  int tid = threadIdx.x, w = tid >> 6, l = tid & 63, lr = l & 15, lq = l >> 4;
  int bi = blockIdx.x;
  int b = bi >> 3, rtp = (bi >> 1) & 3, ch = bi & 1;
  f32x4 a1[2][2], a2[2][2];
#pragma unroll
  for (int i = 0; i < 2; i++)
#pragma unroll
    for (int j = 0; j < 2; j++) { a1[i][j] = (f32x4){0.f,0.f,0.f,0.f}; a2[i][j] = (f32x4){0.f,0.f,0.f,0.f}; }
  for (int kt = 0; kt < 4; kt++) {
    bf16x8 af1[2], af2[2];
#pragma unroll
    for (int rtl = 0; rtl < 2; rtl++) {
      int rt = rtp * 2 + rtl;
      af1[rtl] = ((const bf16x8*)W1apk)[(rt * 4 + kt) * 64 + l];
      af2[rtl] = ((const bf16x8*)W2apk)[(rt * 4 + kt) * 64 + l];
    }
#pragma unroll
    for (int cti = 0; cti < 2; cti++) {
      int ct = w * 4 + ch * 2 + cti;
      bf16x8 bf = *(const bf16x8*)(HAt + (long)(b * 256 + 16 * ct + lr) * 128 + 32 * kt + 8 * lq);
#pragma unroll
      for (int rtl = 0; rtl < 2; rtl++) {
        a1[rtl][cti] = __builtin_amdgcn_mfma_f32_16x16x32_bf16(af1[rtl], bf, a1[rtl][cti], 0, 0, 0);
        a2[rtl][cti] = __builtin_amdgcn_mfma_f32_16x16x32_bf16(af2[rtl], bf, a2[rtl][cti], 0, 0, 0);
      }
    }
  }
#pragma unroll
  for (int rtl = 0; rtl < 2; rtl++)
#pragma unroll
    for (int cti = 0; cti < 2; cti++) {
      int rt = rtp * 2 + rtl, ct = w * 4 + ch * 2 + cti;
      u16x4 p1, p2;
#pragma unroll
      for (int r = 0; r < 4; r++) {
        p1[r] = f2bf(a1[rtl][cti][r]);
        p2[r] = f2bf(fmaxf(a2[rtl][cti][r], 0.f));
      }
      long off = (long)(b * 256 + 16 * ct + lr) * 128 + 16 * rt + 4 * lq;
      *(u16x4*)(W1hAt + off) = p1;
      *(u16x4*)(midT + off) = p2;
    }
}

__global__ __launch_bounds__(256, 2) void g3_kernel(char* __restrict__ ws)
{
  const unsigned short* midT = (const unsigned short*)(ws + O_MIDT);
  const unsigned short* W3apk = (const unsigned short*)(ws + O_W3APK);
  unsigned short* W3r = (unsigned short*)(ws + O_W3R);
  int tid = threadIdx.x, w = tid >> 6, l = tid & 63, lr = l & 15, lq = l >> 4;
  int bi = blockIdx.x;
  int b = bi >> 3, rtp = (bi >> 1) & 3, ch = bi & 1;
  f32x4 acc[2][2];
#pragma unroll
  for (int i = 0; i < 2; i++)
#pragma unroll
    for (int j = 0; j < 2; j++) acc[i][j] = (f32x4){0.f, 0.f, 0.f, 0.f};
  for (int kt = 0; kt < 4; kt++) {
    bf16x8 af[2];
#pragma unroll
    for (int rtl = 0; rtl < 2; rtl++)
      af[rtl] = ((const bf16x8*)W3apk)[((rtp * 2 + rtl) * 4 + kt) * 64 + l];
#pragma unroll
    for (int cti = 0; cti < 2; cti++) {
      int ct = w * 4 + ch * 2 + cti;
      bf16x8 bf = *(const bf16x8*)(midT + (long)(b * 256 + 16 * ct + lr) * 128 + 32 * kt + 8 * lq);
#pragma unroll
      for (int rtl = 0; rtl < 2; rtl++)
        acc[rtl][cti] = __builtin_amdgcn_mfma_f32_16x16x32_bf16(af[rtl], bf, acc[rtl][cti], 0, 0, 0);
    }
  }
#pragma unroll
  for (int rtl = 0; rtl < 2; rtl++)
#pragma unroll
    for (int cti = 0; cti < 2; cti++) {
      int rt = rtp * 2 + rtl, ct = w * 4 + ch * 2 + cti;
#pragma unroll
      for (int r = 0; r < 4; r++)
        W3r[(long)(b * 128 + 16 * rt + 4 * lq + r) * 256 + 16 * ct + lr] = f2bf(acc[rtl][cti][r]);
    }
}

__global__ __launch_bounds__(256, 2) void g4_kernel(char* __restrict__ ws,
    const float* __restrict__ Wfc, float* __restrict__ out)
{
  const unsigned short* W3r = (const unsigned short*)(ws + O_W3R);
  const unsigned short* Apk = (const unsigned short*)(ws + O_APK);
  const unsigned short* W1hAt = (const unsigned short*)(ws + O_W1HAT);
  int tid = threadIdx.x, w = tid >> 6, l = tid & 63, lr = l & 15, lq = l >> 4;
  int bi = blockIdx.x;
  int b = bi >> 2, cq = bi & 3;
  int ct = cq * 4 + w;
  f32x4 acc[8];
#pragma unroll
  for (int i = 0; i < 8; i++) acc[i] = (f32x4){0.f, 0.f, 0.f, 0.f};
  for (int kt = 0; kt < 8; kt++) {
    bf16x8 bfv = ((const bf16x8*)Apk)[(ct * 8 + kt) * 64 + l];
#pragma unroll
    for (int rt = 0; rt < 8; rt++) {
      bf16x8 af = *(const bf16x8*)(W3r + (long)(b * 128 + 16 * rt + lr) * 256 + 32 * kt + 8 * lq);
      acc[rt] = __builtin_amdgcn_mfma_f32_16x16x32_bf16(af, bfv, acc[rt], 0, 0, 0);
    }
  }
  float psum = 0.f;
#pragma unroll
  for (int rt = 0; rt < 8; rt++) {
    float4 wf = *(const float4*)(Wfc + 16 * rt + 4 * lq);
    u16x4 wv = *(const u16x4*)(W1hAt + (long)(b * 256 + 16 * ct + lr) * 128 + 16 * rt + 4 * lq);
    psum += wf.x * (0.1f * acc[rt][0] + 0.9f * bf2f(wv[0]));
    psum += wf.y * (0.1f * acc[rt][1] + 0.9f * bf2f(wv[1]));
    psum += wf.z * (0.1f * acc[rt][2] + 0.9f * bf2f(wv[2]));
    psum += wf.w * (0.1f * acc[rt][3] + 0.9f * bf2f(wv[3]));
  }
  psum += __shfl_xor(psum, 16);
  psum += __shfl_xor(psum, 32);
  if (lq == 0) out[b * 256 + ct * 16 + lr] = __builtin_amdgcn_rcpf(1.f + exp2f(-1.44269504f * psum));
}

// ---------------------------------------------------------------------------
extern "C" void kernel_launch(void* const* d_in, const int* in_sizes, int n_in,
                              void* d_out, int out_size, void* d_ws, size_t ws_size,
                              hipStream_t stream)
{
  const float* x    = (const float*)d_in[0];
  const float* A    = (const float*)d_in[1];
  const float* Wih0 = (const float*)d_in[2];
  const float* Whh0 = (const float*)d_in[3];
  const float* bih0 = (const float*)d_in[4];
  const float* bhh0 = (const float*)d_in[5];
  const float* Wih1 = (const float*)d_in[6];
  const float* Whh1 = (const float*)d_in[7];
  const float* bih1 = (const float*)d_in[8];
  const float* bhh1 = (const float*)d_in[9];
  const float* W1   = (const float*)d_in[10];
  const float* W2   = (const float*)d_in[11];
  const float* W3   = (const float*)d_in[12];
  const float* Wfc  = (const float*)d_in[13];
  char* ws = (char*)d_ws;

  prep_kernel<<<(PREP_TOT + 255) / 256, 256, 0, stream>>>(
      A, Wih0, Whh0, bih0, bhh0, Wih1, Whh1, bih1, bhh1, W1, W2, W3, ws);
  prepx_kernel<<<8192, 256, 0, stream>>>(x, ws);

  size_t need_full = (size_t)O_H1 + 134217728u;  // 8192-row h1
  size_t need_half = (size_t)O_H1 + 67108864u;   // 4096-row h1
  if (ws_size >= need_full) {
    lstm0_k<<<256, 1024, 0, stream>>>(ws, 0);
    lstm1_k<<<256, 1024, 0, stream>>>(ws, 0);
  } else if (ws_size >= need_half) {
    for (int c = 0; c < 2; c++) {
      lstm0_k<<<128, 1024, 0, stream>>>(ws, c * 4096);
      lstm1_k<<<128, 1024, 0, stream>>>(ws, c * 4096);
    }
  } else {
    for (int c = 0; c < 4; c++) {
      lstm0_k<<<64, 1024, 0, stream>>>(ws, c * 2048);
      lstm1_k<<<64, 1024, 0, stream>>>(ws, c * 2048);
    }
  }

  g1_kernel<<<256, 256, 0, stream>>>(ws);
  g2_kernel<<<256, 256, 0, stream>>>(ws);
  g3_kernel<<<256, 256, 0, stream>>>(ws);
  g4_kernel<<<128, 256, 0, stream>>>(ws, Wfc, (float*)d_out);
}

// Round 6
// 275.101 us; speedup vs baseline: 2.4396x; 1.2127x over previous
//
#include <hip/hip_runtime.h>

// ---------------------------------------------------------------------------
// 2-layer LSTM (BN=8192 seqs, T=64, F=16, H=128) + graph mixing stage.
// LSTM gates: G^T = W_packed . h^T (A=weights in VGPR/AGPR, B=h from LDS).
// Unit mapping: wave W, acc s, lane-quad lq -> unit u = 8W + 2lq + s
//   gate-row gr = 16*(2W+s) + 4*lq + p  (p = gate i/f/g/o = acc reg index)
//   => lane's two cells (s=0,1) are ADJACENT units -> single u32 LDS write
//      via v_cvt_pk_bf16_f32.
// MFMA frag conventions (verified rounds 1-5):
//   A-frag: lane l holds A[16*rt + (l&15)][32*kt + 8*(l>>4) + i], i=0..7
//   B-frag: lane l holds B[32*kt + 8*(l>>4) + i][16*ct + (l&15)]
//   D:      lane l, reg r holds D[16*rt + 4*(l>>4) + r][16*ct + (l&15)]
// Round 6: raw v_exp_f32 via __builtin_amdgcn_exp2f (exp2f was routing through
// OCML with range handling = the hidden VALU load), branchless prefetch,
// peeled hTt epilogue.
// ---------------------------------------------------------------------------

typedef __attribute__((ext_vector_type(4))) float f32x4;
typedef __attribute__((ext_vector_type(2))) float f32x2;
typedef __attribute__((ext_vector_type(8))) __bf16 bf16x8;
typedef __attribute__((ext_vector_type(8))) unsigned short u16x8;
typedef __attribute__((ext_vector_type(4))) unsigned short u16x4;

#define DEV static __device__ __forceinline__

DEV unsigned short f2bf(float f) {
  unsigned u = __builtin_bit_cast(unsigned, f);
  u = u + 0x7fffu + ((u >> 16) & 1u);
  return (unsigned short)(u >> 16);
}
DEV float bf2f(unsigned short s) {
  unsigned u = ((unsigned)s) << 16;
  return __builtin_bit_cast(float, u);
}

DEV float fexp2(float x) { return __builtin_amdgcn_exp2f(x); }   // raw v_exp_f32
DEV f32x2 exp2v2(f32x2 x) { f32x2 r; r[0] = fexp2(x[0]); r[1] = fexp2(x[1]); return r; }
DEV f32x2 rcpv2(f32x2 x) {
  f32x2 r; r[0] = __builtin_amdgcn_rcpf(x[0]); r[1] = __builtin_amdgcn_rcpf(x[1]); return r;
}

// Two independent LSTM cells in packed f32x2 lanes; gates per cell i,f,g,o.
// Returns packed bf16 pair (lo = cell s=0, hi = cell s=1).
DEV unsigned cell_pair(f32x2 gi, f32x2 gf, f32x2 gg, f32x2 go, f32x2& c) {
  const float K1 = 1.44269504f, K2 = 2.88539008f;
  f32x2 t1 = exp2v2((f32x2){K2 * gg[0], K2 * gg[1]});
  f32x2 t2 = exp2v2((f32x2){-K1 * gi[0], -K1 * gi[1]});
  f32x2 ef = exp2v2((f32x2){-K1 * gf[0], -K1 * gf[1]});
  f32x2 one = {1.f, 1.f};
  f32x2 d1 = t1 + one;
  f32x2 den1 = d1 * t2 + d1;
  f32x2 it = (t1 - one) * rcpv2(den1);          // sig(i)*tanh(g)
  c = rcpv2(one + ef) * c + it;                 // sig(f)*c + it
  f32x2 t3 = exp2v2((f32x2){K2 * c[0], K2 * c[1]});
  f32x2 t4 = exp2v2((f32x2){-K1 * go[0], -K1 * go[1]});
  f32x2 d3 = t3 + one;
  f32x2 den3 = d3 * t4 + d3;
  f32x2 h = (t3 - one) * rcpv2(den3);           // sig(o)*tanh(c)
  unsigned r;
  asm("v_cvt_pk_bf16_f32 %0, %1, %2" : "=v"(r) : "v"(h[0]), "v"(h[1]));
  return r;
}

// ---------------- workspace layout (bytes) ----------------
#define O_W0PK   0            // 32rt*5kt*64l*8i bf16 = 163840
#define O_W1PK   163840       // 32rt*8kt*64l*8i bf16 = 262144
#define O_APK    425984       // 131072
#define O_W1APK  557056       // 32768
#define O_W2APK  589824       // 32768
#define O_W3APK  622592       // 32768
#define O_BIAS0  655360       // 2048
#define O_BIAS1  657408       // 2048
#define O_HTT    659456       // 2097152  hT^T [32][128][256] bf16
#define O_HAT    2756608      // 2097152
#define O_MIDT   4853760      // 2097152
#define O_W1HAT  6950912      // 2097152
#define O_W3R    9048064      // 2097152
#define O_XPK    11145216     // 33554432 x B-frags (padded K=32, pad col16=1.0)
#define O_H1     44699648     // up to 128 MiB h1 [row][t][128] bf16

#define PREP_TOT 328704

// unit for packed gate-row tile rt, lane-quad lq, within-pair s = rt&1
DEV int gr_unit(int rt, int lq2, int s) { return 8 * (rt >> 1) + 2 * lq2 + s; }

// ---------------- prepass: pack weights -----------------------------------
__global__ void prep_kernel(const float* __restrict__ A,
    const float* __restrict__ Wih0, const float* __restrict__ Whh0,
    const float* __restrict__ bih0, const float* __restrict__ bhh0,
    const float* __restrict__ Wih1, const float* __restrict__ Whh1,
    const float* __restrict__ bih1, const float* __restrict__ bhh1,
    const float* __restrict__ W1, const float* __restrict__ W2,
    const float* __restrict__ W3, char* __restrict__ ws)
{
  int idx = blockIdx.x * blockDim.x + threadIdx.x;
  if (idx >= PREP_TOT) return;
  if (idx < 81920) {                       // W0pk A-frags
    int o = idx, i = o & 7, l = (o >> 3) & 63, f = o >> 9;
    int kt = f % 5, rt = f / 5;
    int lr = l & 15, lq = l >> 4;
    int p = lr & 3, lql = (lr >> 2) & 3;
    int gc = p * 128 + gr_unit(rt, lql, rt & 1);
    float v;
    if (kt < 4) v = Whh0[gc * 128 + 32 * kt + 8 * lq + i];
    else {
      int kk = 8 * lq + i;
      v = (kk < 16) ? Wih0[gc * 16 + kk]
                    : (kk == 16 ? (bih0[gc] + bhh0[gc]) : 0.f);  // bias row
    }
    ((unsigned short*)(ws + O_W0PK))[idx] = f2bf(v);
  } else if (idx < 212992) {               // W1pk: kt<4 = h1-input, kt>=4 = recurrent
    int o = idx - 81920, i = o & 7, l = (o >> 3) & 63, f = o >> 9;
    int kt = f & 7, rt = f >> 3;
    int lr = l & 15, lq = l >> 4;
    int p = lr & 3, lql = (lr >> 2) & 3;
    int gc = p * 128 + gr_unit(rt, lql, rt & 1);
    float v = (kt < 4) ? Wih1[gc * 128 + 32 * kt + 8 * lq + i]
                       : Whh1[gc * 128 + 32 * (kt - 4) + 8 * lq + i];
    ((unsigned short*)(ws + O_W1PK))[o] = f2bf(v);
  } else if (idx < 278528) {               // Apk = sigmoid(A) B-frags
    int o = idx - 212992, i = o & 7, l = (o >> 3) & 63, f = o >> 9;
    int kt = f & 7, ct = f >> 3;
    int n = 32 * kt + 8 * (l >> 4) + i;
    int lc = 16 * ct + (l & 15);
    float e = fexp2(-1.44269504f * A[n * 256 + lc]);
    ((unsigned short*)(ws + O_APK))[o] = f2bf(__builtin_amdgcn_rcpf(1.f + e));
  } else if (idx < 327680) {               // W1/W2/W3 A-frags (graph stage)
    int o = idx - 278528;
    int m = o >> 14;
    int oo = o & 16383;
    int i = oo & 7, l = (oo >> 3) & 63, f = oo >> 9;
    int kt = f & 3, rt = f >> 2;
    int g = 16 * rt + (l & 15);
    int k = 32 * kt + 8 * (l >> 4) + i;
    const float* W = (m == 0) ? W1 : (m == 1) ? W2 : W3;
    unsigned short* dst = (unsigned short*)(ws + ((m == 0) ? O_W1APK : (m == 1) ? O_W2APK : O_W3APK));
    dst[oo] = f2bf(W[g * 128 + k]);
  } else if (idx < 328192) {
    int c = idx - 327680;
    ((float*)(ws + O_BIAS0))[c] = bih0[c] + bhh0[c];
  } else {
    int c = idx - 328192;
    ((float*)(ws + O_BIAS1))[c] = bih1[c] + bhh1[c];
  }
}

// x -> padded B-frag bf16; pad column k=16 = 1.0 (bias multiplier)
__global__ void prepx_kernel(const float* __restrict__ x, char* __restrict__ ws)
{
  int tid = blockIdx.x * 256 + threadIdx.x;     // 0 .. 2097151
  int dat = (tid < 1048576) ? 1 : 0;
  int id = tid & 1048575;
  int half = id & 1, t = (id >> 1) & 63, row = id >> 7;
  u16x8 v = (u16x8)0;
  if (dat) {
    const float* p = x + ((long)row * 64 + t) * 16 + 8 * half;
    float4 a = *(const float4*)p;
    float4 b = *(const float4*)(p + 4);
    v[0] = f2bf(a.x); v[1] = f2bf(a.y); v[2] = f2bf(a.z); v[3] = f2bf(a.w);
    v[4] = f2bf(b.x); v[5] = f2bf(b.y); v[6] = f2bf(b.z); v[7] = f2bf(b.w);
  } else if (half == 0) {
    v[0] = 0x3F80;                              // k=16 -> 1.0f (bias column)
  }
  int lane = (dat ? 0 : 32) + half * 16 + (row & 15);
  int rt = row >> 4;
  ((u16x8*)(ws + O_XPK))[(rt * 64 + t) * 64 + lane] = v;
}

// ---------------- LSTM layer 0: 32 rows/block, 16 waves, 1 barrier/step ----
__global__ __launch_bounds__(1024, 4) void lstm0_k(char* __restrict__ ws, int row_base)
{
  const unsigned short* W0pk = (const unsigned short*)(ws + O_W0PK);
  const unsigned short* xpk = (const unsigned short*)(ws + O_XPK);
  unsigned short* h1 = (unsigned short*)(ws + O_H1);

  int tid = threadIdx.x;
  int Wv = tid >> 6, l = tid & 63, lr = l & 15, lq = l >> 4;
  int lrow = blockIdx.x * 32;
  long grow0 = (long)row_base + lrow;

  __shared__ unsigned char hlds[2][8192];  // h state [32 rows][128 u] swizzled
  ((u16x8*)hlds[0])[tid] = (u16x8)0;       // zero both buffers (16 KB)

  bf16x8 Af[2][5];                          // A-tiles rt = 2Wv+s
#pragma unroll
  for (int s = 0; s < 2; s++)
#pragma unroll
    for (int kt = 0; kt < 5; kt++)
      Af[s][kt] = ((const bf16x8*)W0pk)[(((2 * Wv + s) * 5) + kt) * 64 + l];

  f32x2 c_st[2] = {{0.f, 0.f}, {0.f, 0.f}};  // [ct], lanes = s

  int rd[2][4], whp[2];
#pragma unroll
  for (int ct = 0; ct < 2; ct++) {
#pragma unroll
    for (int kt = 0; kt < 4; kt++)
      rd[ct][kt] = (16 * ct + lr) * 256 + ((64 * kt + 16 * lq) ^ ((lr & 7) << 4));
    whp[ct] = (16 * ct + lr) * 256 + ((16 * Wv + 4 * lq) ^ ((lr & 7) << 4));
  }

  // coalesced h1 bounce: thread -> rows pr, pr+16, u32 col sj
  int pr = tid >> 6, sj = tid & 63;
  int sld0 = pr * 256 + ((4 * sj) ^ ((pr & 7) << 4));
  int sld1 = (pr + 16) * 256 + ((4 * sj) ^ ((pr & 7) << 4));
  unsigned short* st0 = h1 + (long)(lrow + pr) * 8192 + 2 * sj;
  unsigned short* st1 = h1 + (long)(lrow + pr + 16) * 8192 + 2 * sj;

  const bf16x8* xp0 = (const bf16x8*)xpk + ((grow0 >> 4) + 0) * 4096 + l;
  const bf16x8* xp1 = (const bf16x8*)xpk + ((grow0 >> 4) + 1) * 4096 + l;
  bf16x8 xb[2] = {xp0[0], xp1[0]};
  __syncthreads();

  for (int t = 0; t < 64; t++) {
    const unsigned char* rbuf = hlds[t & 1];
    unsigned char* wbuf = hlds[(t & 1) ^ 1];
    int tn = (t < 63) ? t + 1 : 63;          // branchless prefetch index
    bf16x8 xbn0 = xp0[tn * 64];
    bf16x8 xbn1 = xp1[tn * 64];

    f32x4 acc[2][2];
#pragma unroll
    for (int ct = 0; ct < 2; ct++)
#pragma unroll
      for (int s = 0; s < 2; s++) acc[ct][s] = (f32x4){0.f, 0.f, 0.f, 0.f};
#pragma unroll
    for (int kt = 0; kt < 4; kt++) {
      bf16x8 hb0 = *(const bf16x8*)(rbuf + rd[0][kt]);
      bf16x8 hb1 = *(const bf16x8*)(rbuf + rd[1][kt]);
      acc[0][0] = __builtin_amdgcn_mfma_f32_16x16x32_bf16(Af[0][kt], hb0, acc[0][0], 0, 0, 0);
      acc[0][1] = __builtin_amdgcn_mfma_f32_16x16x32_bf16(Af[1][kt], hb0, acc[0][1], 0, 0, 0);
      acc[1][0] = __builtin_amdgcn_mfma_f32_16x16x32_bf16(Af[0][kt], hb1, acc[1][0], 0, 0, 0);
      acc[1][1] = __builtin_amdgcn_mfma_f32_16x16x32_bf16(Af[1][kt], hb1, acc[1][1], 0, 0, 0);
    }
    acc[0][0] = __builtin_amdgcn_mfma_f32_16x16x32_bf16(Af[0][4], xb[0], acc[0][0], 0, 0, 0);
    acc[0][1] = __builtin_amdgcn_mfma_f32_16x16x32_bf16(Af[1][4], xb[0], acc[0][1], 0, 0, 0);
    acc[1][0] = __builtin_amdgcn_mfma_f32_16x16x32_bf16(Af[0][4], xb[1], acc[1][0], 0, 0, 0);
    acc[1][1] = __builtin_amdgcn_mfma_f32_16x16x32_bf16(Af[1][4], xb[1], acc[1][1], 0, 0, 0);
#pragma unroll
    for (int ct = 0; ct < 2; ct++) {
      f32x2 gi = {acc[ct][0][0], acc[ct][1][0]};
      f32x2 gf = {acc[ct][0][1], acc[ct][1][1]};
      f32x2 gg = {acc[ct][0][2], acc[ct][1][2]};
      f32x2 go = {acc[ct][0][3], acc[ct][1][3]};
      *(unsigned*)(wbuf + whp[ct]) = cell_pair(gi, gf, gg, go, c_st[ct]);
    }
    xb[0] = xbn0; xb[1] = xbn1;
    __syncthreads();
    // h(t) complete in wbuf: coalesced global store (256B contiguous per wave)
    *(unsigned*)(st0 + t * 128) = *(const unsigned*)(hlds[(t & 1) ^ 1] + sld0);
    *(unsigned*)(st1 + t * 128) = *(const unsigned*)(hlds[(t & 1) ^ 1] + sld1);
  }
}

// ---------------- LSTM layer 1: 32 rows/block, 16 waves --------------------
__global__ __launch_bounds__(1024, 4) void lstm1_k(char* __restrict__ ws, int row_base)
{
  const unsigned short* W1pk = (const unsigned short*)(ws + O_W1PK);
  const float* bias1 = (const float*)(ws + O_BIAS1);
  const unsigned short* h1 = (const unsigned short*)(ws + O_H1);
  unsigned short* hTt = (unsigned short*)(ws + O_HTT);

  int tid = threadIdx.x;
  int Wv = tid >> 6, l = tid & 63, lr = l & 15, lq = l >> 4;
  int lrow = blockIdx.x * 32;
  long grow0 = (long)row_base + lrow;

  __shared__ unsigned char hlds[2][8192];  // layer-1 h state
  __shared__ unsigned char h1s[2][8192];   // staged h1 input
  ((u16x8*)hlds[0])[tid] = (u16x8)0;

  // h1 staging: thread -> rows prow, prow+16, u32 col pc
  int prow = tid >> 6, pc = tid & 63;
  const unsigned short* s0 = h1 + (long)(lrow + prow) * 8192 + 2 * pc;
  const unsigned short* s1 = h1 + (long)(lrow + prow + 16) * 8192 + 2 * pc;
  int d0 = prow * 256 + ((4 * pc) ^ ((prow & 7) << 4));
  int d1 = (prow + 16) * 256 + ((4 * pc) ^ ((prow & 7) << 4));
  *(unsigned*)(h1s[0] + d0) = *(const unsigned*)s0;   // t = 0
  *(unsigned*)(h1s[0] + d1) = *(const unsigned*)s1;

  bf16x8 Af[2][8];
#pragma unroll
  for (int s = 0; s < 2; s++)
#pragma unroll
    for (int kt = 0; kt < 8; kt++)
      Af[s][kt] = ((const bf16x8*)W1pk)[(((2 * Wv + s) * 8) + kt) * 64 + l];

  f32x4 bias_c[2];
#pragma unroll
  for (int s = 0; s < 2; s++)
#pragma unroll
    for (int r = 0; r < 4; r++)
      bias_c[s][r] = bias1[r * 128 + 8 * Wv + 2 * lq + s];

  f32x2 c_st[2] = {{0.f, 0.f}, {0.f, 0.f}};

  int rd[2][4], whp[2];
#pragma unroll
  for (int ct = 0; ct < 2; ct++) {
#pragma unroll
    for (int kt = 0; kt < 4; kt++)
      rd[ct][kt] = (16 * ct + lr) * 256 + ((64 * kt + 16 * lq) ^ ((lr & 7) << 4));
    whp[ct] = (16 * ct + lr) * 256 + ((16 * Wv + 4 * lq) ^ ((lr & 7) << 4));
  }
  __syncthreads();

  for (int t = 0; t < 64; t++) {
    const unsigned char* rbuf = hlds[t & 1];
    unsigned char* wbuf = hlds[(t & 1) ^ 1];
    const unsigned char* h1r = h1s[t & 1];
    unsigned char* h1w = h1s[(t & 1) ^ 1];
    int tn = (t < 63) ? t + 1 : 63;
    unsigned pf0 = *(const unsigned*)(s0 + tn * 128);
    unsigned pf1 = *(const unsigned*)(s1 + tn * 128);

    f32x4 acc[2][2];
#pragma unroll
    for (int ct = 0; ct < 2; ct++) {
      acc[ct][0] = bias_c[0]; acc[ct][1] = bias_c[1];
    }
#pragma unroll
    for (int kt = 0; kt < 4; kt++) {
      bf16x8 xb0 = *(const bf16x8*)(h1r + rd[0][kt]);
      bf16x8 xb1 = *(const bf16x8*)(h1r + rd[1][kt]);
      acc[0][0] = __builtin_amdgcn_mfma_f32_16x16x32_bf16(Af[0][kt], xb0, acc[0][0], 0, 0, 0);
      acc[0][1] = __builtin_amdgcn_mfma_f32_16x16x32_bf16(Af[1][kt], xb0, acc[0][1], 0, 0, 0);
      acc[1][0] = __builtin_amdgcn_mfma_f32_16x16x32_bf16(Af[0][kt], xb1, acc[1][0], 0, 0, 0);
      acc[1][1] = __builtin_amdgcn_mfma_f32_16x16x32_bf16(Af[1][kt], xb1, acc[1][1], 0, 0, 0);
    }
#pragma unroll
    for (int kt = 0; kt < 4; kt++) {
      bf16x8 hb0 = *(const bf16x8*)(rbuf + rd[0][kt]);
      bf16x8 hb1 = *(const bf16x8*)(rbuf + rd[1][kt]);
      acc[0][0] = __builtin_amdgcn_mfma_f32_16x16x32_bf16(Af[0][4 + kt], hb0, acc[0][0], 0, 0, 0);
      acc[0][1] = __builtin_amdgcn_mfma_f32_16x16x32_bf16(Af[1][4 + kt], hb0, acc[0][1], 0, 0, 0);
      acc[1][0] = __builtin_amdgcn_mfma_f32_16x16x32_bf16(Af[0][4 + kt], hb1, acc[1][0], 0, 0, 0);
      acc[1][1] = __builtin_amdgcn_mfma_f32_16x16x32_bf16(Af[1][4 + kt], hb1, acc[1][1], 0, 0, 0);
    }
#pragma unroll
    for (int ct = 0; ct < 2; ct++) {
      f32x2 gi = {acc[ct][0][0], acc[ct][1][0]};
      f32x2 gf = {acc[ct][0][1], acc[ct][1][1]};
      f32x2 gg = {acc[ct][0][2], acc[ct][1][2]};
      f32x2 go = {acc[ct][0][3], acc[ct][1][3]};
      *(unsigned*)(wbuf + whp[ct]) = cell_pair(gi, gf, gg, go, c_st[ct]);
    }
    *(unsigned*)(h1w + d0) = pf0;
    *(unsigned*)(h1w + d1) = pf1;
    __syncthreads();
  }

  // peeled epilogue: final h (t=63) lives in hlds[0]; scatter to hTt [b][u][n]
#pragma unroll
  for (int ct = 0; ct < 2; ct++) {
    unsigned hp = *(const unsigned*)(hlds[0] + whp[ct]);
    long grow = grow0 + 16 * ct + lr;
    long base = ((grow >> 8) * 128) * 256 + (grow & 255);
    int u0 = 8 * Wv + 2 * lq;
    hTt[base + (long)u0 * 256] = (unsigned short)(hp & 0xffff);
    hTt[base + (long)(u0 + 1) * 256] = (unsigned short)(hp >> 16);
  }
}

// ---------------- graph stage (unchanged, verified) ------------------------
__global__ __launch_bounds__(256, 2) void g1_kernel(char* __restrict__ ws)
{
  const unsigned short* hTt = (const unsigned short*)(ws + O_HTT);
  const unsigned short* Apk = (const unsigned short*)(ws + O_APK);
  unsigned short* HAt = (unsigned short*)(ws + O_HAT);
  int tid = threadIdx.x, w = tid >> 6, l = tid & 63, lr = l & 15, lq = l >> 4;
  int bi = blockIdx.x;
  int b = bi >> 3, rtp = (bi >> 1) & 3, ch = bi & 1;
  f32x4 acc[2][2];
#pragma unroll
  for (int i = 0; i < 2; i++)
#pragma unroll
    for (int j = 0; j < 2; j++) acc[i][j] = (f32x4){0.f, 0.f, 0.f, 0.f};
  for (int kt = 0; kt < 8; kt++) {
    bf16x8 af[2];
#pragma unroll
    for (int rtl = 0; rtl < 2; rtl++) {
      int rt = rtp * 2 + rtl;
      af[rtl] = *(const bf16x8*)(hTt + (long)(b * 128 + 16 * rt + lr) * 256 + 32 * kt + 8 * lq);
    }
#pragma unroll
    for (int cti = 0; cti < 2; cti++) {
      int ct = w * 4 + ch * 2 + cti;
      bf16x8 bf = ((const bf16x8*)Apk)[(ct * 8 + kt) * 64 + l];
#pragma unroll
      for (int rtl = 0; rtl < 2; rtl++)
        acc[rtl][cti] = __builtin_amdgcn_mfma_f32_16x16x32_bf16(af[rtl], bf, acc[rtl][cti], 0, 0, 0);
    }
  }
#pragma unroll
  for (int rtl = 0; rtl < 2; rtl++)
#pragma unroll
    for (int cti = 0; cti < 2; cti++) {
      int rt = rtp * 2 + rtl, ct = w * 4 + ch * 2 + cti;
      u16x4 pk;
#pragma unroll
      for (int r = 0; r < 4; r++) pk[r] = f2bf(acc[rtl][cti][r]);
      *(u16x4*)(HAt + (long)(b * 256 + 16 * ct + lr) * 128 + 16 * rt + 4 * lq) = pk;
    }
}

__global__ __launch_bounds__(256, 2) void g2_kernel(char* __restrict__ ws)
{
  const unsigned short* HAt = (const unsigned short*)(ws + O_HAT);
  const unsigned short* W1apk = (const unsigned short*)(ws + O_W1APK);
  const unsigned short* W2apk = (const unsigned short*)(ws + O_W2APK);
  unsigned short* W1hAt = (unsigned short*)(ws + O_W1HAT);
  unsigned short* midT = (unsigned short*)(ws + O_MIDT);
  int tid = threadIdx.x, w = tid >> 6, l = tid & 63, lr = l & 15, lq = l >> 4;
  int bi = blockIdx.x;
  int b = bi >> 3, rtp = (bi >> 1) & 3, ch = bi & 1;
  f32x4 a1[2][2], a2[2][2];
#pragma unroll
  for (int i = 0; i < 2; i++)
#pragma unroll
    for (int j = 0; j < 2; j++) { a1[i][j] = (f32x4){0.f,0.f,0.f,0.f}; a2[i][j] = (f32x4){0.f,0.f,0.f,0.f}; }
  for (int kt = 0; kt < 4; kt++) {
    bf16x8 af1[2], af2[2];
#pragma unroll
    for (int rtl = 0; rtl < 2; rtl++) {
      int rt = rtp * 2 + rtl;
      af1[rtl] = ((const bf16x8*)W1apk)[(rt * 4 + kt) * 64 + l];
      af2[rtl] = ((const bf16x8*)W2apk)[(rt * 4 + kt) * 64 + l];
    }
#pragma unroll
    for (int cti = 0; cti < 2; cti++) {
      int ct = w * 4 + ch * 2 + cti;
      bf16x8 bf = *(const bf16x8*)(HAt + (long)(b * 256 + 16 * ct + lr) * 128 + 32 * kt + 8 * lq);
#pragma unroll
      for (int rtl = 0; rtl < 2; rtl++) {
        a1[rtl][cti] = __builtin_amdgcn_mfma_f32_16x16x32_bf16(af1[rtl], bf, a1[rtl][cti], 0, 0, 0);
        a2[rtl][cti] = __builtin_amdgcn_mfma_f32_16x16x32_bf16(af2[rtl], bf, a2[rtl][cti], 0, 0, 0);
      }
    }
  }
#pragma unroll
  for (int rtl = 0; rtl < 2; rtl++)
#pragma unroll
    for (int cti = 0; cti < 2; cti++) {
      int rt = rtp * 2 + rtl, ct = w * 4 + ch * 2 + cti;
      u16x4 p1, p2;
#pragma unroll
      for (int r = 0; r < 4; r++) {
        p1[r] = f2bf(a1[rtl][cti][r]);
        p2[r] = f2bf(fmaxf(a2[rtl][cti][r], 0.f));
      }
      long off = (long)(b * 256 + 16 * ct + lr) * 128 + 16 * rt + 4 * lq;
      *(u16x4*)(W1hAt + off) = p1;
      *(u16x4*)(midT + off) = p2;
    }
}

__global__ __launch_bounds__(256, 2) void g3_kernel(char* __restrict__ ws)
{
  const unsigned short* midT = (const unsigned short*)(ws + O_MIDT);
  const unsigned short* W3apk = (const unsigned short*)(ws + O_W3APK);
  unsigned short* W3r = (unsigned short*)(ws + O_W3R);
  int tid = threadIdx.x, w = tid >> 6, l = tid & 63, lr = l & 15, lq = l >> 4;
  int bi = blockIdx.x;
  int b = bi >> 3, rtp = (bi >> 1) & 3, ch = bi & 1;
  f32x4 acc[2][2];
#pragma unroll
  for (int i = 0; i < 2; i++)
#pragma unroll
    for (int j = 0; j < 2; j++) acc[i][j] = (f32x4){0.f, 0.f, 0.f, 0.f};
  for (int kt = 0; kt < 4; kt++) {
    bf16x8 af[2];
#pragma unroll
    for (int rtl = 0; rtl < 2; rtl++)
      af[rtl] = ((const bf16x8*)W3apk)[((rtp * 2 + rtl) * 4 + kt) * 64 + l];
#pragma unroll
    for (int cti = 0; cti < 2; cti++) {
      int ct = w * 4 + ch * 2 + cti;
      bf16x8 bf = *(const bf16x8*)(midT + (long)(b * 256 + 16 * ct + lr) * 128 + 32 * kt + 8 * lq);
#pragma unroll
      for (int rtl = 0; rtl < 2; rtl++)
        acc[rtl][cti] = __builtin_amdgcn_mfma_f32_16x16x32_bf16(af[rtl], bf, acc[rtl][cti], 0, 0, 0);
    }
  }
#pragma unroll
  for (int rtl = 0; rtl < 2; rtl++)
#pragma unroll
    for (int cti = 0; cti < 2; cti++) {
      int rt = rtp * 2 + rtl, ct = w * 4 + ch * 2 + cti;
#pragma unroll
      for (int r = 0; r < 4; r++)
        W3r[(long)(b * 128 + 16 * rt + 4 * lq + r) * 256 + 16 * ct + lr] = f2bf(acc[rtl][cti][r]);
    }
}

__global__ __launch_bounds__(256, 2) void g4_kernel(char* __restrict__ ws,
    const float* __restrict__ Wfc, float* __restrict__ out)
{
  const unsigned short* W3r = (const unsigned short*)(ws + O_W3R);
  const unsigned short* Apk = (const unsigned short*)(ws + O_APK);
  const unsigned short* W1hAt = (const unsigned short*)(ws + O_W1HAT);
  int tid = threadIdx.x, w = tid >> 6, l = tid & 63, lr = l & 15, lq = l >> 4;
  int bi = blockIdx.x;
  int b = bi >> 2, cq = bi & 3;
  int ct = cq * 4 + w;
  f32x4 acc[8];
#pragma unroll
  for (int i = 0; i < 8; i++) acc[i] = (f32x4){0.f, 0.f, 0.f, 0.f};
  for (int kt = 0; kt < 8; kt++) {
    bf16x8 bfv = ((const bf16x8*)Apk)[(ct * 8 + kt) * 64 + l];
#pragma unroll
    for (int rt = 0; rt < 8; rt++) {
      bf16x8 af = *(const bf16x8*)(W3r + (long)(b * 128 + 16 * rt + lr) * 256 + 32 * kt + 8 * lq);
      acc[rt] = __builtin_amdgcn_mfma_f32_16x16x32_bf16(af, bfv, acc[rt], 0, 0, 0);
    }
  }
  float psum = 0.f;
#pragma unroll
  for (int rt = 0; rt < 8; rt++) {
    float4 wf = *(const float4*)(Wfc + 16 * rt + 4 * lq);
    u16x4 wv = *(const u16x4*)(W1hAt + (long)(b * 256 + 16 * ct + lr) * 128 + 16 * rt + 4 * lq);
    psum += wf.x * (0.1f * acc[rt][0] + 0.9f * bf2f(wv[0]));
    psum += wf.y * (0.1f * acc[rt][1] + 0.9f * bf2f(wv[1]));
    psum += wf.z * (0.1f * acc[rt][2] + 0.9f * bf2f(wv[2]));
    psum += wf.w * (0.1f * acc[rt][3] + 0.9f * bf2f(wv[3]));
  }
  psum += __shfl_xor(psum, 16);
  psum += __shfl_xor(psum, 32);
  if (lq == 0) out[b * 256 + ct * 16 + lr] = __builtin_amdgcn_rcpf(1.f + fexp2(-1.44269504f * psum));
}

// ---------------------------------------------------------------------------
extern "C" void kernel_launch(void* const* d_in, const int* in_sizes, int n_in,
                              void* d_out, int out_size, void* d_ws, size_t ws_size,
                              hipStream_t stream)
{
  const float* x    = (const float*)d_in[0];
  const float* A    = (const float*)d_in[1];
  const float* Wih0 = (const float*)d_in[2];
  const float* Whh0 = (const float*)d_in[3];
  const float* bih0 = (const float*)d_in[4];
  const float* bhh0 = (const float*)d_in[5];
  const float* Wih1 = (const float*)d_in[6];
  const float* Whh1 = (const float*)d_in[7];
  const float* bih1 = (const float*)d_in[8];
  const float* bhh1 = (const float*)d_in[9];
  const float* W1   = (const float*)d_in[10];
  const float* W2   = (const float*)d_in[11];
  const float* W3   = (const float*)d_in[12];
  const float* Wfc  = (const float*)d_in[13];
  char* ws = (char*)d_ws;

  prep_kernel<<<(PREP_TOT + 255) / 256, 256, 0, stream>>>(
      A, Wih0, Whh0, bih0, bhh0, Wih1, Whh1, bih1, bhh1, W1, W2, W3, ws);
  prepx_kernel<<<8192, 256, 0, stream>>>(x, ws);

  size_t need_full = (size_t)O_H1 + 134217728u;  // 8192-row h1
  size_t need_half = (size_t)O_H1 + 67108864u;   // 4096-row h1
  if (ws_size >= need_full) {
    lstm0_k<<<256, 1024, 0, stream>>>(ws, 0);
    lstm1_k<<<256, 1024, 0, stream>>>(ws, 0);
  } else if (ws_size >= need_half) {
    for (int c = 0; c < 2; c++) {
      lstm0_k<<<128, 1024, 0, stream>>>(ws, c * 4096);
      lstm1_k<<<128, 1024, 0, stream>>>(ws, c * 4096);
    }
  } else {
    for (int c = 0; c < 4; c++) {
      lstm0_k<<<64, 1024, 0, stream>>>(ws, c * 2048);
      lstm1_k<<<64, 1024, 0, stream>>>(ws, c * 2048);
    }
  }

  g1_kernel<<<256, 256, 0, stream>>>(ws);
  g2_kernel<<<256, 256, 0, stream>>>(ws);
  g3_kernel<<<256, 256, 0, stream>>>(ws);
  g4_kernel<<<128, 256, 0, stream>>>(ws, Wfc, (float*)d_out);
}